// Round 1
// 1178.409 us; speedup vs baseline: 1.3904x; 1.3904x over previous
//
#include <hip/hip_runtime.h>

#define N_GRAPHS 2048
#define CAP 2048            // per-graph edge bucket capacity

// ---- workspace layout (float offsets) ----
// NOTE: P2 aliases EBUF (edge pipeline fully completes before conv12 runs)
#define WS_CUR  0           // 2048 int
#define WS_EBUF 2048        // 2048*2048 u32 (packed src|loc<<17)
#define WS_P2   2048        // 2048*6700 f32 (aliases EBUF; consumed before write)
#define WS_Z    13723648    // 2048*900
#define WS_H1   15566848    // 2048*256 (fc1 out; ALSO hosts bw weights until conv12 done)
#define WS_WF   16091136    // converted f32 weights (347834)
#define WS_FLAG 16438970    // int flag

// ---- converted-weight offsets within wf ----
// conv weights stored TRANSPOSED: W[c][k][o]  (o fastest)
#define W_SAGE_WL 0
#define W_SAGE_BL 1000
#define W_SAGE_WR 1100
#define W_CW1     2100      // [21][3][100]
#define W_CB1     8400
#define W_CW2     8500      // [100][3][100]
#define W_CB2     38500
#define W_CW3     38600
#define W_CB3     68600
#define W_CW4     68700
#define W_CB4     98700
#define W_BNG     98800
#define W_BNB     99700
#define W_FC1W    100600
#define W_FC1B    331000
#define W_FC2W    331256
#define W_FC2B    347640
#define W_FC3W    347704
#define W_FC3B    347832
#define W_TOT     347834

// ---- MFMA fragment-layout conv weights (u16 offsets within bw = ws+WS_H1) ----
// layout Bw[Kchunk][o:112][8] bf16; K = k*CS + c  (conv1 CS=24 K'=96, conv2 CS=104 K'=320)
#define BW2H_OFF 0
#define BW2L_OFF 35840
#define BW1H_OFF 71680
#define BW1L_OFF 82432
#define BW_TOT   93184      // u16 elems (186368 B, fits easily in H1 region)

typedef __attribute__((ext_vector_type(8))) short bf16x8;  // 8 bf16 (4 VGPRs)
typedef __attribute__((ext_vector_type(4))) float f32x4;   // MFMA accumulator

#define MFMA16(a, b, c) __builtin_amdgcn_mfma_f32_16x16x32_bf16((a), (b), (c), 0, 0, 0)

__device__ __forceinline__ float bf2f(unsigned short u){
  union { unsigned int ui; float f; } v; v.ui = ((unsigned int)u) << 16; return v.f;
}
__device__ __forceinline__ unsigned short f2bf(float f){
  union { float f; unsigned int ui; } v; v.f = f;
  unsigned int u = v.ui;
  return (unsigned short)((u + 0x7fffu + ((u >> 16) & 1u)) >> 16);
}
__device__ __forceinline__ float max3f(float a, float b, float c){
  return fmaxf(a, fmaxf(b, c));
}

// ---------------- dtype detection ----------------
__global__ void detect_dtype(const unsigned int* __restrict__ bng, int* __restrict__ flag){
  if (threadIdx.x == 0 && blockIdx.x == 0)
    flag[0] = (bng[0] == 0x3F803F80u) ? 1 : 0;   // bf16 "1.0,1.0" pair vs f32 1.0
}

// ---------------- weight conversion (+ conv transpose) ----------------
struct WP { const void* p[19]; };

__global__ __launch_bounds__(256) void cvt_weights(WP wp, const int* __restrict__ flag,
                                                   float* __restrict__ dst){
  const int i = blockIdx.x*256 + threadIdx.x;
  if (i >= W_TOT) return;
  const int isbf = flag[0];
  int seg = 0, off = i;
  #define SEGC(s, o) if (i >= (o)) { seg = (s); off = i - (o); }
  SEGC(1, W_SAGE_BL) SEGC(2, W_SAGE_WR) SEGC(3, W_CW1) SEGC(4, W_CB1)
  SEGC(5, W_CW2) SEGC(6, W_CB2) SEGC(7, W_CW3) SEGC(8, W_CB3)
  SEGC(9, W_CW4) SEGC(10, W_CB4) SEGC(11, W_BNG) SEGC(12, W_BNB)
  SEGC(13, W_FC1W) SEGC(14, W_FC1B) SEGC(15, W_FC2W) SEGC(16, W_FC2B)
  SEGC(17, W_FC3W) SEGC(18, W_FC3B)
  #undef SEGC
  int src = off;
  if (seg == 3){                         // conv1: dst [c][k][o] <- src [o][c][k], c<21
    int c = off / 300, r = off - c*300, k = r / 100, o = r - k*100;
    src = o*63 + c*3 + k;
  } else if (seg == 5 || seg == 7 || seg == 9){  // conv2/3/4: c<100
    int c = off / 300, r = off - c*300, k = r / 100, o = r - k*100;
    src = o*300 + c*3 + k;
  }
  if (isbf) dst[i] = bf2f(((const unsigned short*)wp.p[seg])[src]);
  else      dst[i] = ((const float*)wp.p[seg])[src];
}

// ---------------- MFMA weight prep: hi/lo bf16 split in fragment layout ---------
// B operand of mfma_f32_16x16x32_bf16: lane holds col=lane&15, K-chunk=(lane>>4)*8.
// Memory layout Bw[ch = K>>3][o][jj] so each lane reads one contiguous 16B chunk.
__global__ __launch_bounds__(256) void prep_bw(const float* __restrict__ wf,
                                               unsigned short* __restrict__ bw){
  const int i = blockIdx.x*256 + threadIdx.x;
  if (i >= 46592) return;                // 35840 (conv2) + 10752 (conv1)
  float w = 0.f; int hidx, lidx;
  if (i < 35840){                        // conv2: K = k*104 + c, K' padded to 320
    const int jj = i & 7, rest = i >> 3;
    const int o = rest % 112, ch = rest / 112;
    const int K = ch*8 + jj;
    const int k = K / 104, c = K - k*104;
    if (K < 312 && c < 100 && o < 100) w = wf[W_CW2 + c*300 + k*100 + o];
    hidx = BW2H_OFF + i; lidx = BW2L_OFF + i;
  } else {                               // conv1: K = k*24 + c, K' padded to 96
    const int ii = i - 35840;
    const int jj = ii & 7, rest = ii >> 3;
    const int o = rest % 112, ch = rest / 112;
    const int K = ch*8 + jj;
    const int k = K / 24, c = K - k*24;
    if (K < 72 && c < 21 && o < 100) w = wf[W_CW1 + c*300 + k*100 + o];
    hidx = BW1H_OFF + ii; lidx = BW1L_OFF + ii;
  }
  const unsigned short hi = f2bf(w);
  bw[hidx] = hi;
  bw[lidx] = f2bf(w - bf2f(hi));         // residual: effective weight precision ~2^-18
}

// ---------------- edge bucketing: single-pass scatter into fixed buckets ----
__global__ __launch_bounds__(256) void edge_scatter(const int* __restrict__ ei,
                                                    int* __restrict__ cur,
                                                    unsigned int* __restrict__ ebuf,
                                                    const int E){
  const int e = blockIdx.x*256 + threadIdx.x;
  if (e >= E) return;
  const unsigned int src = (unsigned int)ei[e];
  const int dst = ei[E + e];
  const int g = dst >> 6, loc = dst & 63;
  const int pos = atomicAdd(&cur[g], 1);
  if (pos < CAP) ebuf[(size_t)g*CAP + pos] = src | ((unsigned int)loc << 17);
}

// ---------------- per-graph SAGE (deg in LDS, weighted sum in regs) ----------
__global__ __launch_bounds__(256) void graph_all(const unsigned int* __restrict__ ebuf,
                                                 const int* __restrict__ cur,
                                                 const void* __restrict__ x1v,
                                                 const int* __restrict__ flag,
                                                 const float* __restrict__ wf,
                                                 float* __restrict__ z){
  const int g = blockIdx.x, tid = threadIdx.x;
  const int wave = tid >> 6, lane = tid & 63;
  __shared__ float degs[64];
  __shared__ float smp[40];
  __shared__ float sm[10], sx[10];
  if (tid < 64) degs[tid] = 0.f;
  __syncthreads();
  const unsigned int* eb = ebuf + (size_t)g*CAP;
  const int n = min(cur[g], CAP);
  const int isbf = flag[0];
  for (int e = tid; e < n; e += 256)
    atomicAdd(&degs[eb[e] >> 17], 1.0f);
  __syncthreads();
  float acc[10];
  #pragma unroll
  for (int f = 0; f < 10; ++f) acc[f] = 0.f;
  for (int e = tid; e < n; e += 256){
    const unsigned int p = eb[e];
    const unsigned int src = p & 0x1FFFFu;
    const float w = 1.0f / fmaxf(degs[p >> 17], 1.0f);
    if (isbf){
      const unsigned int* xr = (const unsigned int*)x1v + (size_t)src*5;
      #pragma unroll
      for (int k = 0; k < 5; ++k){
        unsigned int u = xr[k];
        acc[2*k]   += w * bf2f((unsigned short)(u & 0xffffu));
        acc[2*k+1] += w * bf2f((unsigned short)(u >> 16));
      }
    } else {
      const float2* xr = (const float2*)((const float*)x1v + (size_t)src*10);
      #pragma unroll
      for (int k = 0; k < 5; ++k){
        float2 u = xr[k];
        acc[2*k] += w*u.x; acc[2*k+1] += w*u.y;
      }
    }
  }
  #pragma unroll
  for (int f = 0; f < 10; ++f){
    float v = acc[f];
    #pragma unroll
    for (int o = 32; o > 0; o >>= 1) v += __shfl_down(v, o);
    if (lane == 0) smp[wave*10 + f] = v;
  }
  if (wave == 0){
    const int node = g*64 + lane;
    float xv[10];
    if (isbf){
      const unsigned int* xr = (const unsigned int*)x1v + (size_t)node*5;
      #pragma unroll
      for (int k = 0; k < 5; ++k){
        unsigned int u = xr[k];
        xv[2*k]   = bf2f((unsigned short)(u & 0xffffu));
        xv[2*k+1] = bf2f((unsigned short)(u >> 16));
      }
    } else {
      const float* xr = (const float*)x1v + (size_t)node*10;
      #pragma unroll
      for (int k = 0; k < 10; ++k) xv[k] = xr[k];
    }
    #pragma unroll
    for (int f = 0; f < 10; ++f){
      float v = xv[f];
      #pragma unroll
      for (int o = 32; o > 0; o >>= 1) v += __shfl_down(v, o);
      if (lane == 0) sx[f] = v;
    }
  }
  __syncthreads();
  if (tid < 10) sm[tid] = smp[tid] + smp[10+tid] + smp[20+tid] + smp[30+tid];
  __syncthreads();
  if (tid < 100){
    const float* Wl = wf + W_SAGE_WL + tid*10;
    const float* Wr = wf + W_SAGE_WR + tid*10;
    float a = 64.0f * wf[W_SAGE_BL + tid];
    #pragma unroll
    for (int k = 0; k < 10; ++k) a += sm[k]*Wl[k] + sx[k]*Wr[k];
    z[(size_t)g*900 + tid] = a;
  }
}

// ---------------- conv dot helper (still used by conv34) --------------------
template<int NC, int TO, bool BF16IN>
__device__ __forceinline__ void conv_dot(const void* __restrict__ inb, int stride, int bi,
                                         const float* __restrict__ wT, float* acc){
  #pragma unroll 2
  for (int c = 0; c < NC; ++c){
    float i0, i1, i2;
    if constexpr (BF16IN){
      const unsigned short* row = (const unsigned short*)inb + c*stride + bi;
      i0 = bf2f(row[0]); i1 = bf2f(row[1]); i2 = bf2f(row[2]);
    } else {
      const float* row = (const float*)inb + c*stride + bi;
      i0 = row[0]; i1 = row[1]; i2 = row[2];
    }
    const float* wr = wT + c*300;
    #pragma unroll
    for (int j = 0; j < TO; ++j)
      acc[j] = fmaf(i2, wr[200+j], fmaf(i1, wr[100+j], fmaf(i0, wr[j], acc[j])));
  }
}

// ============================================================================
// conv1+pool1+conv2+pool2 via MFMA. Swapped GEMM: A = im2col(input) with rows =
// positions, B = W^T with cols = out-channels, so D rows (4/lane-group) are
// consecutive positions -> pool3 done in registers (+1 shfl per straddle).
// Supers = 48 rows = 16 pool windows (lcm(16,3)). Lane-group G = 4*mt + (lane>>4)
// holds rows 4G..4G+3; role = G%3 decides which windows this group owns.
// POOL_EMIT verified by full 48-row case analysis (all 16 windows exactly once).
// ============================================================================
#define POOL_EMIT(MT_, A_, PUA_, PUN_, ST_) { \
  const int G_ = (MT_)*4 + t; \
  const int a3_ = G_ / 3, role_ = G_ - a3_*3; \
  const float rdn_ = __shfl_down((PUA_), 16); \
  const float rnx_ = __shfl((PUN_), col); \
  const float rc_ = (t == 3) ? rnx_ : rdn_; \
  const float w1_ = max3f((A_)[0], (A_)[1], (A_)[2]); \
  const float w2_ = fmaxf((A_)[3], rc_); \
  const float w3_ = max3f((A_)[2], (A_)[3], rc_); \
  const float w4_ = max3f((A_)[1], (A_)[2], (A_)[3]); \
  const int j1_ = 4*a3_ + (role_ == 0 ? 0 : (role_ == 1 ? 2 : 3)); \
  const float v1_ = (role_ == 0 ? w1_ : (role_ == 1 ? w3_ : w4_)); \
  ST_(j1_, v1_) \
  if (role_ == 0) ST_((j1_ + 1), w2_) \
}

__global__ __launch_bounds__(512, 8) void conv12_half(const void* __restrict__ x2v,
                                                      const int* __restrict__ flag,
                                                      const float* __restrict__ wf,
                                                      float* __restrict__ p2g,
                                                      const unsigned short* __restrict__ bw){
  __shared__ __align__(16) unsigned char lds[40192];
  unsigned short* XT  = (unsigned short*)lds;             // [326][24]  x2 transposed, bf16
  unsigned short* P1T = (unsigned short*)(lds + 15648);   // [118][104] pool1 out transposed
  const int h = blockIdx.x, g = blockIdx.y, tid = threadIdx.x;
  const int wave = __builtin_amdgcn_readfirstlane(tid >> 6);
  const int lane = tid & 63;
  const int t = lane >> 4, col = lane & 15;
  const float NEG = -__builtin_inff();
  const int qs = h ? 100 : 0;
  const int nq = h ? 100 : 102;     // conv1/pool1 q-range computed by this half
  const int xs = h ? 300 : 0;

  // zero P1T (covers halo rows, c-padding 100..103, and all garbage-read rows)
  for (int i = tid; i < 6136; i += 512) ((unsigned int*)P1T)[i] = 0u;
  // stage X transposed: XT[xi][c] = x2[g][c][xs-1+xi], zero outside [0,600) / c>=21
  if (flag[0]){
    const unsigned short* src = (const unsigned short*)x2v + (size_t)g*12600;
    for (int i = tid; i < 21*326; i += 512){
      const int c = i / 326, xi = i - c*326;
      const int x = xs - 1 + xi;
      XT[xi*24 + c] = (x >= 0 && x < 600) ? src[c*600 + x] : (unsigned short)0;
    }
  } else {
    const float* src = (const float*)x2v + (size_t)g*12600;
    for (int i = tid; i < 21*326; i += 512){
      const int c = i / 326, xi = i - c*326;
      const int x = xs - 1 + xi;
      XT[xi*24 + c] = (x >= 0 && x < 600) ? f2bf(src[c*600 + x]) : (unsigned short)0;
    }
  }
  for (int i = tid; i < 326; i += 512){
    XT[i*24 + 21] = 0; XT[i*24 + 22] = 0; XT[i*24 + 23] = 0;
  }
  __syncthreads();

  // ---- conv1 (M=pos, N=100ch, K'=96) + pool1(pad0) -> P1T[q+2][c] ----
  // units: 7 supers x 7 N-tiles; super sg covers x_local in [48sg, 48sg+48)
  for (int u = wave; u < 49; u += 8){
    const int sg = u / 7, nt = u - sg*7;
    const int o = nt*16 + col;
    const int MTn = (sg < 6) ? 3 : (h ? 1 : 2);
    f32x4 acc0 = {0.f,0.f,0.f,0.f}, acc1 = {0.f,0.f,0.f,0.f}, acc2 = {0.f,0.f,0.f,0.f};
    const unsigned short* bh = bw + BW1H_OFF + (size_t)(t*112 + o)*8;
    const unsigned short* bl = bw + BW1L_OFF + (size_t)(t*112 + o)*8;
    const int xbase = sg*48 + col;
    #pragma unroll
    for (int s = 0; s < 3; ++s){
      const int K = 32*s + 8*t;
      const int k = (K >= 72) ? 3 : (K >= 48) ? 2 : (K >= 24) ? 1 : 0;
      const int c0 = K - 24*k;
      const unsigned short* ap = XT + (xbase + k)*24 + c0;
      const bf16x8 av0 = *(const bf16x8*)ap;
      const bf16x8 bvh = *(const bf16x8*)(bh + s*3584);
      const bf16x8 bvl = *(const bf16x8*)(bl + s*3584);
      acc0 = MFMA16(av0, bvh, acc0);
      acc0 = MFMA16(av0, bvl, acc0);
      if (MTn > 1){
        const bf16x8 av1 = *(const bf16x8*)(ap + 16*24);
        acc1 = MFMA16(av1, bvh, acc1);
        acc1 = MFMA16(av1, bvl, acc1);
        if (MTn > 2){
          const bf16x8 av2 = *(const bf16x8*)(ap + 32*24);
          acc2 = MFMA16(av2, bvh, acc2);
          acc2 = MFMA16(av2, bvl, acc2);
        }
      }
    }
    // pool (raw), then bias+lrelu (commutes with max), write P1T transposed
    const float b1 = wf[W_CB1 + (o < 100 ? o : 0)];
    const float pu0 = (((t    ) % 3) == 1) ? fmaxf(acc0[0], acc0[1]) : acc0[0];
    const float pu1 = (((t + 4) % 3) == 1) ? fmaxf(acc1[0], acc1[1]) : acc1[0];
    const float pu2 = (((t + 8) % 3) == 1) ? fmaxf(acc2[0], acc2[1]) : acc2[0];
    #define ST1(jj, vv) { const int q_ = sg*16 + (jj); \
      if (q_ < nq && o < 100){ float v_ = (vv) + b1; v_ = v_ > 0.f ? v_ : 0.01f*v_; \
        P1T[(2 + q_)*104 + o] = f2bf(v_); } }
    POOL_EMIT(0, acc0, pu0, pu1, ST1)
    if (MTn > 1) POOL_EMIT(1, acc1, pu1, pu2, ST1)
    if (MTn > 2) POOL_EMIT(2, acc2, pu2, pu2, ST1)
    #undef ST1
  }
  __syncthreads();

  // ---- conv2 (M=pos m, N=100ch, K'=320) + pool2(pad1) -> p2g[g][o][p] ----
  // supers start at m = 3p-1 (window-aligned); sg=2 is a single M-tile tail
  const int pb = h ? 34 : 0;
  const int plim = h ? 67 : 34;
  for (int u = wave; u < 21; u += 8){
    const int sg = u / 7, nt = u - sg*7;
    const int o = nt*16 + col;
    const int m_b = (h ? 101 : -1) + sg*48;
    const int MTn = (sg < 2) ? 3 : 1;
    f32x4 acc0 = {0.f,0.f,0.f,0.f}, acc1 = {0.f,0.f,0.f,0.f}, acc2 = {0.f,0.f,0.f,0.f};
    const unsigned short* bh = bw + BW2H_OFF + (size_t)(t*112 + o)*8;
    const unsigned short* bl = bw + BW2L_OFF + (size_t)(t*112 + o)*8;
    const int rbase = m_b + col - qs + 1;     // P1T row for (mt=0, k=0)
    #pragma unroll
    for (int s = 0; s < 10; ++s){
      const int K = 32*s + 8*t;
      const int k = (K >= 208) ? 2 : (K >= 104) ? 1 : 0;
      const int c0 = K - 104*k;
      const unsigned short* ap = P1T + (rbase + k)*104 + c0;
      const bf16x8 av0 = *(const bf16x8*)ap;
      const bf16x8 bvh = *(const bf16x8*)(bh + s*3584);
      const bf16x8 bvl = *(const bf16x8*)(bl + s*3584);
      acc0 = MFMA16(av0, bvh, acc0);
      acc0 = MFMA16(av0, bvl, acc0);
      if (MTn > 1){
        const bf16x8 av1 = *(const bf16x8*)(ap + 16*104);
        acc1 = MFMA16(av1, bvh, acc1);
        acc1 = MFMA16(av1, bvl, acc1);
        const bf16x8 av2 = *(const bf16x8*)(ap + 32*104);
        acc2 = MFMA16(av2, bvh, acc2);
        acc2 = MFMA16(av2, bvl, acc2);
      }
    }
    // pool pad: position m=-1 (h0, sg0, row0) must be -inf, not conv(-1)
    if (h == 0 && sg == 0 && t == 0) acc0[0] = NEG;
    const float b2 = wf[W_CB2 + (o < 100 ? o : 0)];
    const float pu0 = (((t    ) % 3) == 1) ? fmaxf(acc0[0], acc0[1]) : acc0[0];
    const float pu1 = (((t + 4) % 3) == 1) ? fmaxf(acc1[0], acc1[1]) : acc1[0];
    const float pu2 = (((t + 8) % 3) == 1) ? fmaxf(acc2[0], acc2[1]) : acc2[0];
    #define ST2(jj, vv) { const int p_ = pb + sg*16 + (jj); \
      if (p_ < plim && o < 100){ float v_ = (vv) + b2; v_ = v_ > 0.f ? v_ : 0.01f*v_; \
        p2g[((size_t)g*100 + o)*67 + p_] = v_; } }
    POOL_EMIT(0, acc0, pu0, pu1, ST2)
    if (MTn > 1){
      POOL_EMIT(1, acc1, pu1, pu2, ST2)
      POOL_EMIT(2, acc2, pu2, pu2, ST2)
    }
    #undef ST2
  }
}

// ---------------- conv3+pool3+conv4+pool4, one block per graph --------------
__global__ __launch_bounds__(512, 8) void conv34(const float* __restrict__ p2g,
                                                 const float* __restrict__ wf,
                                                 float* __restrict__ z){
  __shared__ __align__(16) unsigned char lds[37600];
  float* P2 = (float*)lds;              // [100][69]: p -> idx p+1
  float* P3 = (float*)(lds + 27600);    // [100][25]: p -> idx p+1
  const int g = blockIdx.x, tid = threadIdx.x;
  const int wave = __builtin_amdgcn_readfirstlane(tid >> 6);
  const int lane = tid & 63;
  const float NEG = -__builtin_inff();

  const float* src = p2g + (size_t)g*6700;
  for (int i = tid; i < 6700; i += 512){
    int o = i / 67, p = i - o*67;
    P2[o*69 + p + 1] = src[i];
  }
  if (tid < 100){ P2[tid*69] = 0.f; P2[tid*69 + 68] = 0.f;
                  P3[tid*25] = 0.f; P3[tid*25 + 24] = 0.f; }
  __syncthreads();

  {
    const int tsk = wave;
    const int ob = tsk & 3, lp = tsk >> 2, o0 = ob*25;
    const int l = lp*63 + lane - 1;
    const int bi = min(max(l, 0), 66);
    float acc[25];
    #pragma unroll
    for (int j = 0; j < 25; ++j) acc[j] = 0.f;
    conv_dot<100,25,false>(P2, 69, bi, wf + W_CW3 + o0, acc);
    const bool wrv = (lane < 63) && (lane % 3 == 0);
    const int q = lp*21 + lane/3;
    const bool lv = (l >= 0) && (l < 67);
    #pragma unroll
    for (int j = 0; j < 25; ++j){
      float v = acc[j] + wf[W_CB3 + o0 + j];
      v = v > 0.f ? v : 0.01f*v;
      float pv = lv ? v : NEG;
      float m = fmaxf(pv, fmaxf(__shfl_down(pv,1), __shfl_down(pv,2)));
      if (wrv && q < 23) P3[(o0+j)*25 + 1 + q] = m;
    }
  }
  __syncthreads();

  if (wave < 4){
    const int o0 = wave*25;
    const int l = lane - 1;
    const int bi = min(max(l, 0), 22);
    float acc[25];
    #pragma unroll
    for (int j = 0; j < 25; ++j) acc[j] = 0.f;
    conv_dot<100,25,false>(P3, 25, bi, wf + W_CW4 + o0, acc);
    const bool wrv = (lane < 63) && (lane % 3 == 0);
    const int q = lane/3;
    const bool lv = (l >= 0) && (l < 23);
    #pragma unroll
    for (int j = 0; j < 25; ++j){
      float v = acc[j] + wf[W_CB4 + o0 + j];
      v = v > 0.f ? v : 0.01f*v;
      float pv = lv ? v : NEG;
      float m = fmaxf(pv, fmaxf(__shfl_down(pv,1), __shfl_down(pv,2)));
      if (wrv && q < 8) z[(size_t)g*900 + 100 + (o0+j)*8 + q] = m;
    }
  }
}

// ---------------- BatchNorm over batch axis (exact two-pass) ----------------
__global__ __launch_bounds__(256) void bn_kernel(float* __restrict__ z,
                                                 const float* __restrict__ wf){
  const int f = blockIdx.x;
  const int tid = threadIdx.x;
  float v[8];
  float s = 0.f;
  #pragma unroll
  for (int i = 0; i < 8; ++i){ v[i] = z[(size_t)(tid + i*256)*900 + f]; s += v[i]; }
  __shared__ float red[34];
  #pragma unroll
  for (int off = 32; off > 0; off >>= 1) s += __shfl_down(s, off);
  const int wave = tid >> 6, lane = tid & 63;
  if (lane == 0) red[wave] = s;
  __syncthreads();
  if (tid == 0) red[32] = (red[0]+red[1]+red[2]+red[3]) * (1.0f/2048.0f);
  __syncthreads();
  const float mu = red[32];
  float q = 0.f;
  #pragma unroll
  for (int i = 0; i < 8; ++i){ float d = v[i] - mu; q += d*d; }
  #pragma unroll
  for (int off = 32; off > 0; off >>= 1) q += __shfl_down(q, off);
  if (lane == 0) red[wave] = q;
  __syncthreads();
  if (tid == 0) red[33] = (red[0]+red[1]+red[2]+red[3]) * (1.0f/2048.0f);
  __syncthreads();
  const float var = red[33];
  const float scale = wf[W_BNG + f] / sqrtf(var + 1e-5f);
  const float shift = wf[W_BNB + f] - mu*scale;
  #pragma unroll
  for (int i = 0; i < 8; ++i) z[(size_t)(tid + i*256)*900 + f] = v[i]*scale + shift;
}

// ---------------- fc1 (900->256) + relu, 8 graphs/block (weight reuse) ------
__global__ __launch_bounds__(256) void fc1(const float* __restrict__ z,
                                           const float* __restrict__ wf,
                                           float* __restrict__ h1){
  const int n0 = blockIdx.x*8, tid = threadIdx.x;
  __shared__ __align__(16) float zr[8][900];
  for (int i = tid; i < 8*225; i += 256){
    int r = i / 225, c = i - r*225;
    ((float4*)&zr[r][0])[c] = ((const float4*)(z + (size_t)(n0 + r)*900))[c];
  }
  __syncthreads();
  const float* W = wf + W_FC1W + (size_t)tid*900;
  float acc[8];
  const float b = wf[W_FC1B + tid];
  #pragma unroll
  for (int r = 0; r < 8; ++r) acc[r] = b;
  #pragma unroll 2
  for (int k = 0; k < 900; k += 4){
    float4 wv = *(const float4*)(W + k);
    #pragma unroll
    for (int r = 0; r < 8; ++r)
      acc[r] += wv.x*zr[r][k] + wv.y*zr[r][k+1] + wv.z*zr[r][k+2] + wv.w*zr[r][k+3];
  }
  #pragma unroll
  for (int r = 0; r < 8; ++r)
    h1[(size_t)(n0 + r)*256 + tid] = fmaxf(acc[r], 0.f);
}

// ---------------- fc2 (256->64) + relu + fc3 (64->2), 4 graphs/block --------
__global__ __launch_bounds__(256) void fc23(const float* __restrict__ h1,
                                            const float* __restrict__ wf,
                                            const int* __restrict__ flag,
                                            void* __restrict__ outp){
  const int n0 = blockIdx.x*4, tid = threadIdx.x;
  __shared__ __align__(16) float hr[1024];
  __shared__ float sh2[4][64];
  const float4* src = (const float4*)(h1 + (size_t)n0*256);
  for (int i = tid; i < 256; i += 256) ((float4*)hr)[i] = src[i];
  __syncthreads();
  const int r = tid >> 6, o = tid & 63;
  const float* W = wf + W_FC2W + (size_t)o*256;
  float acc = wf[W_FC2B + o];
  #pragma unroll 4
  for (int k = 0; k < 256; k += 4){
    float4 wv = *(const float4*)(W + k);
    acc += wv.x*hr[r*256+k] + wv.y*hr[r*256+k+1] + wv.z*hr[r*256+k+2] + wv.w*hr[r*256+k+3];
  }
  sh2[r][o] = fmaxf(acc, 0.f);
  __syncthreads();
  if (tid < 8){
    const int rr = tid >> 1, j = tid & 1;
    const float* W3 = wf + W_FC3W + j*64;
    float a = wf[W_FC3B + j];
    #pragma unroll 8
    for (int k = 0; k < 64; ++k) a += sh2[rr][k]*W3[k];
    const int n = n0 + rr;
    if (flag[0]) ((unsigned short*)outp)[n*2 + j] = f2bf(a);
    else         ((float*)outp)[n*2 + j] = a;
  }
}

extern "C" void kernel_launch(void* const* d_in, const int* in_sizes, int n_in,
                              void* d_out, int out_size, void* d_ws, size_t ws_size,
                              hipStream_t stream){
  float* ws = (float*)d_ws;
  int* flag = (int*)(ws + WS_FLAG);
  const int E = in_sizes[2] / 2;

  detect_dtype<<<1, 64, 0, stream>>>((const unsigned int*)d_in[15], flag);
  hipMemsetAsync(ws + WS_CUR, 0, 2048*sizeof(int), stream);

  WP wp;
  for (int k = 0; k < 19; ++k) wp.p[k] = d_in[4 + k];
  cvt_weights<<<(W_TOT + 255)/256, 256, 0, stream>>>(wp, flag, ws + WS_WF);
  prep_bw<<<182, 256, 0, stream>>>(ws + WS_WF, (unsigned short*)(ws + WS_H1));

  edge_scatter<<<(E + 255)/256, 256, 0, stream>>>((const int*)d_in[2], (int*)(ws + WS_CUR),
                                                  (unsigned int*)(ws + WS_EBUF), E);
  graph_all<<<N_GRAPHS, 256, 0, stream>>>((const unsigned int*)(ws + WS_EBUF),
                                          (const int*)(ws + WS_CUR), d_in[0], flag,
                                          ws + WS_WF, ws + WS_Z);
  conv12_half<<<dim3(2, N_GRAPHS), 512, 0, stream>>>(d_in[1], flag, ws + WS_WF, ws + WS_P2,
                                                     (const unsigned short*)(ws + WS_H1));
  conv34<<<N_GRAPHS, 512, 0, stream>>>(ws + WS_P2, ws + WS_WF, ws + WS_Z);
  bn_kernel<<<900, 256, 0, stream>>>(ws + WS_Z, ws + WS_WF);
  fc1<<<N_GRAPHS/8, 256, 0, stream>>>(ws + WS_Z, ws + WS_WF, ws + WS_H1);
  fc23<<<N_GRAPHS/4, 256, 0, stream>>>(ws + WS_H1, ws + WS_WF, flag, d_out);
}

// Round 3
// 849.013 us; speedup vs baseline: 1.9299x; 1.3880x over previous
//
#include <hip/hip_runtime.h>

#define N_GRAPHS 2048
#define CAP 2048            // per-graph edge bucket capacity

// ---- workspace layout (float offsets) ----
// NOTE: P2 aliases EBUF (edge pipeline fully completes before conv12 runs)
#define WS_CUR  0           // 2048 int
#define WS_EBUF 2048        // 2048*2048 u32 (packed src|loc<<17)
#define WS_P2   2048        // p2g: 2048*67*100 f32 transposed [g][p][o] (aliases EBUF)
#define WS_Z    13723648    // 2048*900
#define WS_H1   15566848    // 2048*256 (fc1 out; ALSO hosts bw weights until conv34 done)
#define WS_WF   16091136    // converted f32 weights (347834)
#define WS_FLAG 16438970    // int flag

// ---- converted-weight offsets within wf ----
// conv weights stored TRANSPOSED: W[c][k][o]  (o fastest)
#define W_SAGE_WL 0
#define W_SAGE_BL 1000
#define W_SAGE_WR 1100
#define W_CW1     2100      // [21][3][100]
#define W_CB1     8400
#define W_CW2     8500      // [100][3][100]
#define W_CB2     38500
#define W_CW3     38600
#define W_CB3     68600
#define W_CW4     68700
#define W_CB4     98700
#define W_BNG     98800
#define W_BNB     99700
#define W_FC1W    100600
#define W_FC1B    331000
#define W_FC2W    331256
#define W_FC2B    347640
#define W_FC3W    347704
#define W_FC3B    347832
#define W_TOT     347834

// ---- MFMA fragment-layout conv weights (u16 offsets within bw = ws+WS_H1) ----
// layout Bw[Kchunk][o:112][8] bf16; K = k*CS + c
// conv1: CS=24, K'=96; conv2/3/4: CS=104, K'=320
#define BW2H_OFF 0
#define BW2L_OFF 35840
#define BW1H_OFF 71680
#define BW1L_OFF 82432
#define BW3H_OFF 93184
#define BW3L_OFF 129024
#define BW4H_OFF 164864
#define BW4L_OFF 200704
#define BW_TOT   236544     // u16 elems (473 KB, fits in H1 region)

typedef __attribute__((ext_vector_type(8))) short bf16x8;  // 8 bf16 (4 VGPRs)
typedef __attribute__((ext_vector_type(4))) float f32x4;   // MFMA accumulator

#define MFMA16(a, b, c) __builtin_amdgcn_mfma_f32_16x16x32_bf16((a), (b), (c), 0, 0, 0)

__device__ __forceinline__ float bf2f(unsigned short u){
  union { unsigned int ui; float f; } v; v.ui = ((unsigned int)u) << 16; return v.f;
}
__device__ __forceinline__ unsigned short f2bf(float f){
  union { float f; unsigned int ui; } v; v.f = f;
  unsigned int u = v.ui;
  return (unsigned short)((u + 0x7fffu + ((u >> 16) & 1u)) >> 16);
}
__device__ __forceinline__ float max3f(float a, float b, float c){
  return fmaxf(a, fmaxf(b, c));
}

// ---------------- dtype detection ----------------
__global__ void detect_dtype(const unsigned int* __restrict__ bng, int* __restrict__ flag){
  if (threadIdx.x == 0 && blockIdx.x == 0)
    flag[0] = (bng[0] == 0x3F803F80u) ? 1 : 0;   // bf16 "1.0,1.0" pair vs f32 1.0
}

// ---------------- weight conversion (+ conv transpose) ----------------
struct WP { const void* p[19]; };

__global__ __launch_bounds__(256) void cvt_weights(WP wp, const int* __restrict__ flag,
                                                   float* __restrict__ dst){
  const int i = blockIdx.x*256 + threadIdx.x;
  if (i >= W_TOT) return;
  const int isbf = flag[0];
  int seg = 0, off = i;
  #define SEGC(s, o) if (i >= (o)) { seg = (s); off = i - (o); }
  SEGC(1, W_SAGE_BL) SEGC(2, W_SAGE_WR) SEGC(3, W_CW1) SEGC(4, W_CB1)
  SEGC(5, W_CW2) SEGC(6, W_CB2) SEGC(7, W_CW3) SEGC(8, W_CB3)
  SEGC(9, W_CW4) SEGC(10, W_CB4) SEGC(11, W_BNG) SEGC(12, W_BNB)
  SEGC(13, W_FC1W) SEGC(14, W_FC1B) SEGC(15, W_FC2W) SEGC(16, W_FC2B)
  SEGC(17, W_FC3W) SEGC(18, W_FC3B)
  #undef SEGC
  int src = off;
  if (seg == 3){                         // conv1: dst [c][k][o] <- src [o][c][k], c<21
    int c = off / 300, r = off - c*300, k = r / 100, o = r - k*100;
    src = o*63 + c*3 + k;
  } else if (seg == 5 || seg == 7 || seg == 9){  // conv2/3/4: c<100
    int c = off / 300, r = off - c*300, k = r / 100, o = r - k*100;
    src = o*300 + c*3 + k;
  }
  if (isbf) dst[i] = bf2f(((const unsigned short*)wp.p[seg])[src]);
  else      dst[i] = ((const float*)wp.p[seg])[src];
}

// ---------------- MFMA weight prep: hi/lo bf16 split in fragment layout ---------
// B operand of mfma_f32_16x16x32_bf16: lane holds col=lane&15, K-chunk=(lane>>4)*8.
// Memory layout Bw[ch = K>>3][o][jj] so each lane reads one contiguous 16B chunk.
__global__ __launch_bounds__(256) void prep_bw(const float* __restrict__ wf,
                                               unsigned short* __restrict__ bw){
  const int i = blockIdx.x*256 + threadIdx.x;
  if (i >= 118272) return;   // 35840(c2) + 10752(c1) + 35840(c3) + 35840(c4)
  float w = 0.f; int hidx, lidx;
  if (i < 35840 || i >= 46592){          // conv2/3/4: K = k*104 + c, K' = 320
    int ii, wbase, hoff, loff;
    if (i < 35840)      { ii = i;         wbase = W_CW2; hoff = BW2H_OFF; loff = BW2L_OFF; }
    else if (i < 82432) { ii = i - 46592; wbase = W_CW3; hoff = BW3H_OFF; loff = BW3L_OFF; }
    else                { ii = i - 82432; wbase = W_CW4; hoff = BW4H_OFF; loff = BW4L_OFF; }
    const int jj = ii & 7, rest = ii >> 3;
    const int o = rest % 112, ch = rest / 112;
    const int K = ch*8 + jj;
    const int k = K / 104, c = K - k*104;
    if (K < 312 && c < 100 && o < 100) w = wf[wbase + c*300 + k*100 + o];
    hidx = hoff + ii; lidx = loff + ii;
  } else {                               // conv1: K = k*24 + c, K' = 96
    const int ii = i - 35840;
    const int jj = ii & 7, rest = ii >> 3;
    const int o = rest % 112, ch = rest / 112;
    const int K = ch*8 + jj;
    const int k = K / 24, c = K - k*24;
    if (K < 72 && c < 21 && o < 100) w = wf[W_CW1 + c*300 + k*100 + o];
    hidx = BW1H_OFF + ii; lidx = BW1L_OFF + ii;
  }
  const unsigned short hi = f2bf(w);
  bw[hidx] = hi;
  bw[lidx] = f2bf(w - bf2f(hi));         // residual: effective weight precision ~2^-18
}

// ---------------- edge bucketing: single-pass scatter into fixed buckets ----
__global__ __launch_bounds__(256) void edge_scatter(const int* __restrict__ ei,
                                                    int* __restrict__ cur,
                                                    unsigned int* __restrict__ ebuf,
                                                    const int E){
  const int e = blockIdx.x*256 + threadIdx.x;
  if (e >= E) return;
  const unsigned int src = (unsigned int)ei[e];
  const int dst = ei[E + e];
  const int g = dst >> 6, loc = dst & 63;
  const int pos = atomicAdd(&cur[g], 1);
  if (pos < CAP) ebuf[(size_t)g*CAP + pos] = src | ((unsigned int)loc << 17);
}

// ---------------- per-graph SAGE (deg in LDS, weighted sum in regs) ----------
__global__ __launch_bounds__(256) void graph_all(const unsigned int* __restrict__ ebuf,
                                                 const int* __restrict__ cur,
                                                 const void* __restrict__ x1v,
                                                 const int* __restrict__ flag,
                                                 const float* __restrict__ wf,
                                                 float* __restrict__ z){
  const int g = blockIdx.x, tid = threadIdx.x;
  const int wave = tid >> 6, lane = tid & 63;
  __shared__ float degs[64];
  __shared__ float smp[40];
  __shared__ float sm[10], sx[10];
  if (tid < 64) degs[tid] = 0.f;
  __syncthreads();
  const unsigned int* eb = ebuf + (size_t)g*CAP;
  const int n = min(cur[g], CAP);
  const int isbf = flag[0];
  for (int e = tid; e < n; e += 256)
    atomicAdd(&degs[eb[e] >> 17], 1.0f);
  __syncthreads();
  float acc[10];
  #pragma unroll
  for (int f = 0; f < 10; ++f) acc[f] = 0.f;
  for (int e = tid; e < n; e += 256){
    const unsigned int p = eb[e];
    const unsigned int src = p & 0x1FFFFu;
    const float w = 1.0f / fmaxf(degs[p >> 17], 1.0f);
    if (isbf){
      const unsigned int* xr = (const unsigned int*)x1v + (size_t)src*5;
      #pragma unroll
      for (int k = 0; k < 5; ++k){
        unsigned int u = xr[k];
        acc[2*k]   += w * bf2f((unsigned short)(u & 0xffffu));
        acc[2*k+1] += w * bf2f((unsigned short)(u >> 16));
      }
    } else {
      const float2* xr = (const float2*)((const float*)x1v + (size_t)src*10);
      #pragma unroll
      for (int k = 0; k < 5; ++k){
        float2 u = xr[k];
        acc[2*k] += w*u.x; acc[2*k+1] += w*u.y;
      }
    }
  }
  #pragma unroll
  for (int f = 0; f < 10; ++f){
    float v = acc[f];
    #pragma unroll
    for (int o = 32; o > 0; o >>= 1) v += __shfl_down(v, o);
    if (lane == 0) smp[wave*10 + f] = v;
  }
  if (wave == 0){
    const int node = g*64 + lane;
    float xv[10];
    if (isbf){
      const unsigned int* xr = (const unsigned int*)x1v + (size_t)node*5;
      #pragma unroll
      for (int k = 0; k < 5; ++k){
        unsigned int u = xr[k];
        xv[2*k]   = bf2f((unsigned short)(u & 0xffffu));
        xv[2*k+1] = bf2f((unsigned short)(u >> 16));
      }
    } else {
      const float* xr = (const float*)x1v + (size_t)node*10;
      #pragma unroll
      for (int k = 0; k < 10; ++k) xv[k] = xr[k];
    }
    #pragma unroll
    for (int f = 0; f < 10; ++f){
      float v = xv[f];
      #pragma unroll
      for (int o = 32; o > 0; o >>= 1) v += __shfl_down(v, o);
      if (lane == 0) sx[f] = v;
    }
  }
  __syncthreads();
  if (tid < 10) sm[tid] = smp[tid] + smp[10+tid] + smp[20+tid] + smp[30+tid];
  __syncthreads();
  if (tid < 100){
    const float* Wl = wf + W_SAGE_WL + tid*10;
    const float* Wr = wf + W_SAGE_WR + tid*10;
    float a = 64.0f * wf[W_SAGE_BL + tid];
    #pragma unroll
    for (int k = 0; k < 10; ++k) a += sm[k]*Wl[k] + sx[k]*Wr[k];
    z[(size_t)g*900 + tid] = a;
  }
}

// ============================================================================
// MFMA conv machinery (verified R0/R1 on conv1/conv2). Swapped GEMM:
// A = im2col(input), rows = positions; B = W^T, cols = out-channels. D rows
// (4/lane-group) are consecutive positions -> pool3 done in registers.
// Supers = 48 rows = 16 pool windows. Lane-group G = 4*mt + t holds local rows
// 4G..4G+3; role = G%3 decides which windows this group owns.
// ============================================================================
#define POOL_EMIT(MT_, A_, PUA_, PUN_, ST_) { \
  const int G_ = (MT_)*4 + t; \
  const int a3_ = G_ / 3, role_ = G_ - a3_*3; \
  const float rdn_ = __shfl_down((PUA_), 16); \
  const float rnx_ = __shfl((PUN_), col); \
  const float rc_ = (t == 3) ? rnx_ : rdn_; \
  const float w1_ = max3f((A_)[0], (A_)[1], (A_)[2]); \
  const float w2_ = fmaxf((A_)[3], rc_); \
  const float w3_ = max3f((A_)[2], (A_)[3], rc_); \
  const float w4_ = max3f((A_)[1], (A_)[2], (A_)[3]); \
  const int j1_ = 4*a3_ + (role_ == 0 ? 0 : (role_ == 1 ? 2 : 3)); \
  const float v1_ = (role_ == 0 ? w1_ : (role_ == 1 ? w3_ : w4_)); \
  ST_(j1_, v1_) \
  if (role_ == 0) ST_((j1_ + 1), w2_) \
}

__global__ __launch_bounds__(512, 8) void conv12_half(const void* __restrict__ x2v,
                                                      const int* __restrict__ flag,
                                                      const float* __restrict__ wf,
                                                      float* __restrict__ p2g,
                                                      const unsigned short* __restrict__ bw){
  __shared__ __align__(16) unsigned char lds[40192];
  unsigned short* XT  = (unsigned short*)lds;             // [326][24]  x2 transposed, bf16
  unsigned short* P1T = (unsigned short*)(lds + 15648);   // [118][104] pool1 out transposed
  const int h = blockIdx.x, g = blockIdx.y, tid = threadIdx.x;
  const int wave = __builtin_amdgcn_readfirstlane(tid >> 6);
  const int lane = tid & 63;
  const int t = lane >> 4, col = lane & 15;
  const float NEG = -__builtin_inff();
  const int qs = h ? 100 : 0;
  const int nq = h ? 100 : 102;     // conv1/pool1 q-range computed by this half
  const int xs = h ? 300 : 0;

  // zero P1T (covers halo rows, c-padding 100..103, and all garbage-read rows)
  for (int i = tid; i < 6136; i += 512) ((unsigned int*)P1T)[i] = 0u;
  // stage X transposed: XT[xi][c] = x2[g][c][xs-1+xi], zero outside [0,600) / c>=21
  if (flag[0]){
    const unsigned short* src = (const unsigned short*)x2v + (size_t)g*12600;
    for (int i = tid; i < 21*326; i += 512){
      const int c = i / 326, xi = i - c*326;
      const int x = xs - 1 + xi;
      XT[xi*24 + c] = (x >= 0 && x < 600) ? src[c*600 + x] : (unsigned short)0;
    }
  } else {
    const float* src = (const float*)x2v + (size_t)g*12600;
    for (int i = tid; i < 21*326; i += 512){
      const int c = i / 326, xi = i - c*326;
      const int x = xs - 1 + xi;
      XT[xi*24 + c] = (x >= 0 && x < 600) ? f2bf(src[c*600 + x]) : (unsigned short)0;
    }
  }
  for (int i = tid; i < 326; i += 512){
    XT[i*24 + 21] = 0; XT[i*24 + 22] = 0; XT[i*24 + 23] = 0;
  }
  __syncthreads();

  // ---- conv1 (M=pos, N=100ch, K'=96) + pool1(pad0) -> P1T[q+2][c] ----
  for (int u = wave; u < 49; u += 8){
    const int sg = u / 7, nt = u - sg*7;
    const int o = nt*16 + col;
    const int MTn = (sg < 6) ? 3 : (h ? 1 : 2);
    f32x4 acc0 = {0.f,0.f,0.f,0.f}, acc1 = {0.f,0.f,0.f,0.f}, acc2 = {0.f,0.f,0.f,0.f};
    const unsigned short* bh = bw + BW1H_OFF + (size_t)(t*112 + o)*8;
    const unsigned short* bl = bw + BW1L_OFF + (size_t)(t*112 + o)*8;
    const int xbase = sg*48 + col;
    #pragma unroll
    for (int s = 0; s < 3; ++s){
      const int K = 32*s + 8*t;
      const int k = (K >= 72) ? 3 : (K >= 48) ? 2 : (K >= 24) ? 1 : 0;
      const int c0 = K - 24*k;
      const unsigned short* ap = XT + (xbase + k)*24 + c0;
      const bf16x8 av0 = *(const bf16x8*)ap;
      const bf16x8 bvh = *(const bf16x8*)(bh + s*3584);
      const bf16x8 bvl = *(const bf16x8*)(bl + s*3584);
      acc0 = MFMA16(av0, bvh, acc0);
      acc0 = MFMA16(av0, bvl, acc0);
      if (MTn > 1){
        const bf16x8 av1 = *(const bf16x8*)(ap + 16*24);
        acc1 = MFMA16(av1, bvh, acc1);
        acc1 = MFMA16(av1, bvl, acc1);
        if (MTn > 2){
          const bf16x8 av2 = *(const bf16x8*)(ap + 32*24);
          acc2 = MFMA16(av2, bvh, acc2);
          acc2 = MFMA16(av2, bvl, acc2);
        }
      }
    }
    const float b1 = wf[W_CB1 + (o < 100 ? o : 0)];
    const float pu0 = (((t    ) % 3) == 1) ? fmaxf(acc0[0], acc0[1]) : acc0[0];
    const float pu1 = (((t + 4) % 3) == 1) ? fmaxf(acc1[0], acc1[1]) : acc1[0];
    const float pu2 = (((t + 8) % 3) == 1) ? fmaxf(acc2[0], acc2[1]) : acc2[0];
    #define ST1(jj, vv) { const int q_ = sg*16 + (jj); \
      if (q_ < nq && o < 100){ float v_ = (vv) + b1; v_ = v_ > 0.f ? v_ : 0.01f*v_; \
        P1T[(2 + q_)*104 + o] = f2bf(v_); } }
    POOL_EMIT(0, acc0, pu0, pu1, ST1)
    if (MTn > 1) POOL_EMIT(1, acc1, pu1, pu2, ST1)
    if (MTn > 2) POOL_EMIT(2, acc2, pu2, pu2, ST1)
    #undef ST1
  }
  __syncthreads();

  // ---- conv2 (M=pos m, N=100ch, K'=320) + pool2(pad1) -> p2g[g][p][o] f32 ----
  const int pb = h ? 34 : 0;
  const int plim = h ? 67 : 34;
  for (int u = wave; u < 21; u += 8){
    const int sg = u / 7, nt = u - sg*7;
    const int o = nt*16 + col;
    const int m_b = (h ? 101 : -1) + sg*48;
    const int MTn = (sg < 2) ? 3 : 1;
    f32x4 acc0 = {0.f,0.f,0.f,0.f}, acc1 = {0.f,0.f,0.f,0.f}, acc2 = {0.f,0.f,0.f,0.f};
    const unsigned short* bh = bw + BW2H_OFF + (size_t)(t*112 + o)*8;
    const unsigned short* bl = bw + BW2L_OFF + (size_t)(t*112 + o)*8;
    const int rbase = m_b + col - qs + 1;     // P1T row for (mt=0, k=0)
    #pragma unroll
    for (int s = 0; s < 10; ++s){
      const int K = 32*s + 8*t;
      const int k = (K >= 208) ? 2 : (K >= 104) ? 1 : 0;
      const int c0 = K - 104*k;
      const unsigned short* ap = P1T + (rbase + k)*104 + c0;
      const bf16x8 av0 = *(const bf16x8*)ap;
      const bf16x8 bvh = *(const bf16x8*)(bh + s*3584);
      const bf16x8 bvl = *(const bf16x8*)(bl + s*3584);
      acc0 = MFMA16(av0, bvh, acc0);
      acc0 = MFMA16(av0, bvl, acc0);
      if (MTn > 1){
        const bf16x8 av1 = *(const bf16x8*)(ap + 16*104);
        acc1 = MFMA16(av1, bvh, acc1);
        acc1 = MFMA16(av1, bvl, acc1);
        const bf16x8 av2 = *(const bf16x8*)(ap + 32*104);
        acc2 = MFMA16(av2, bvh, acc2);
        acc2 = MFMA16(av2, bvl, acc2);
      }
    }
    if (h == 0 && sg == 0 && t == 0) acc0[0] = NEG;   // pool pad m=-1
    const float b2 = wf[W_CB2 + (o < 100 ? o : 0)];
    const float pu0 = (((t    ) % 3) == 1) ? fmaxf(acc0[0], acc0[1]) : acc0[0];
    const float pu1 = (((t + 4) % 3) == 1) ? fmaxf(acc1[0], acc1[1]) : acc1[0];
    const float pu2 = (((t + 8) % 3) == 1) ? fmaxf(acc2[0], acc2[1]) : acc2[0];
    #define ST2(jj, vv) { const int p_ = pb + sg*16 + (jj); \
      if (p_ < plim && o < 100){ float v_ = (vv) + b2; v_ = v_ > 0.f ? v_ : 0.01f*v_; \
        p2g[((size_t)g*67 + p_)*100 + o] = v_; } }
    POOL_EMIT(0, acc0, pu0, pu1, ST2)
    if (MTn > 1){
      POOL_EMIT(1, acc1, pu1, pu2, ST2)
      POOL_EMIT(2, acc2, pu2, pu2, ST2)
    }
    #undef ST2
  }
}

// ---------------- conv3+pool3+conv4+pool4 via MFMA, one block per graph -----
// Activations kept near-f32: LDS holds hi/lo bf16 pairs; each K-step does
// Ah*Bh + Ah*Bl + Al*Bh (dropped Al*Bl ~ 2^-16 relative).
// conv3: M = m in [-1,78] (5 M-tiles over 2 supers), N = 100, K' = 320
// conv4: M = m in [-1,30] (2 M-tiles, 1 super),      N = 100, K' = 320
__global__ __launch_bounds__(512, 4) void conv34(const float* __restrict__ p2g,
                                                 const float* __restrict__ wf,
                                                 const unsigned short* __restrict__ bw,
                                                 float* __restrict__ z){
  __shared__ __align__(16) unsigned char lds[48672];
  unsigned short* P2H = (unsigned short*)lds;            // [82][104], row = p+2
  unsigned short* P2L = (unsigned short*)(lds + 17056);
  unsigned short* P3H = (unsigned short*)(lds + 34112);  // [35][104], row = q+2
  unsigned short* P3L = (unsigned short*)(lds + 41392);
  const int g = blockIdx.x, tid = threadIdx.x;
  const int wave = __builtin_amdgcn_readfirstlane(tid >> 6);
  const int lane = tid & 63;
  const int t = lane >> 4, col = lane & 15;
  const float NEG = -__builtin_inff();

  // zero everything (halo rows, pad cols, garbage-read rows), then fill
  for (int i = tid; i < 12168; i += 512) ((unsigned int*)lds)[i] = 0u;
  __syncthreads();
  {
    const float* srcf = p2g + (size_t)g*6700;
    for (int i = tid; i < 6700; i += 512){
      const int p = i / 100, o = i - p*100;
      const float v = srcf[i];
      const unsigned short hi = f2bf(v);
      P2H[(p + 2)*104 + o] = hi;
      P2L[(p + 2)*104 + o] = f2bf(v - bf2f(hi));
    }
  }
  __syncthreads();

  // ---- conv3 (K'=320) + pool3(pad1): P2 -> P3[q+2][o], q in [0,23) ----
  for (int u = wave; u < 14; u += 8){
    const int sg = u / 7, nt = u - sg*7;
    const int o = nt*16 + col;
    const int m_b = -1 + 48*sg;
    const int MTn = sg ? 2 : 3;
    f32x4 acc0 = {0.f,0.f,0.f,0.f}, acc1 = {0.f,0.f,0.f,0.f}, acc2 = {0.f,0.f,0.f,0.f};
    const unsigned short* bh = bw + BW3H_OFF + (size_t)(t*112 + o)*8;
    const unsigned short* bl = bw + BW3L_OFF + (size_t)(t*112 + o)*8;
    const int rbase = m_b + col + 1;          // P2 row for (mt=0, k=0)
    #pragma unroll
    for (int s = 0; s < 10; ++s){
      const int K = 32*s + 8*t;
      const int k = (K >= 208) ? 2 : (K >= 104) ? 1 : 0;
      const int c0 = K - 104*k;
      const int aoff = (rbase + k)*104 + c0;
      const bf16x8 bvh = *(const bf16x8*)(bh + s*3584);
      const bf16x8 bvl = *(const bf16x8*)(bl + s*3584);
      const bf16x8 ah0 = *(const bf16x8*)(P2H + aoff);
      const bf16x8 al0 = *(const bf16x8*)(P2L + aoff);
      acc0 = MFMA16(ah0, bvh, acc0);
      acc0 = MFMA16(ah0, bvl, acc0);
      acc0 = MFMA16(al0, bvh, acc0);
      const bf16x8 ah1 = *(const bf16x8*)(P2H + aoff + 16*104);
      const bf16x8 al1 = *(const bf16x8*)(P2L + aoff + 16*104);
      acc1 = MFMA16(ah1, bvh, acc1);
      acc1 = MFMA16(ah1, bvl, acc1);
      acc1 = MFMA16(al1, bvh, acc1);
      if (MTn > 2){
        const bf16x8 ah2 = *(const bf16x8*)(P2H + aoff + 32*104);
        const bf16x8 al2 = *(const bf16x8*)(P2L + aoff + 32*104);
        acc2 = MFMA16(ah2, bvh, acc2);
        acc2 = MFMA16(ah2, bvl, acc2);
        acc2 = MFMA16(al2, bvh, acc2);
      }
    }
    if (sg == 0 && t == 0) acc0[0] = NEG;     // pool pad m=-1
    if (sg == 1 && t == 1) acc1[0] = NEG;     // pool pad m=67
    const float b3 = wf[W_CB3 + (o < 100 ? o : 0)];
    const float pu0 = (((t    ) % 3) == 1) ? fmaxf(acc0[0], acc0[1]) : acc0[0];
    const float pu1 = (((t + 4) % 3) == 1) ? fmaxf(acc1[0], acc1[1]) : acc1[0];
    const float pu2 = (((t + 8) % 3) == 1) ? fmaxf(acc2[0], acc2[1]) : acc2[0];
    #define ST3(jj, vv) { const int q_ = sg*16 + (jj); \
      if (q_ < 23 && o < 100){ float v_ = (vv) + b3; v_ = v_ > 0.f ? v_ : 0.01f*v_; \
        const unsigned short hi_ = f2bf(v_); \
        P3H[(2 + q_)*104 + o] = hi_; \
        P3L[(2 + q_)*104 + o] = f2bf(v_ - bf2f(hi_)); } }
    POOL_EMIT(0, acc0, pu0, pu1, ST3)
    POOL_EMIT(1, acc1, pu1, pu2, ST3)
    if (MTn > 2) POOL_EMIT(2, acc2, pu2, pu2, ST3)
    #undef ST3
  }
  __syncthreads();

  // ---- conv4 (K'=320) + pool4(pad1): P3 -> z[g][100 + o*8 + q], q in [0,8) ----
  if (wave < 7){
    const int o = wave*16 + col;
    f32x4 acc0 = {0.f,0.f,0.f,0.f}, acc1 = {0.f,0.f,0.f,0.f};
    const unsigned short* bh = bw + BW4H_OFF + (size_t)(t*112 + o)*8;
    const unsigned short* bl = bw + BW4L_OFF + (size_t)(t*112 + o)*8;
    const int rbase = col;                    // m_b = -1: row = m+1+k
    #pragma unroll
    for (int s = 0; s < 10; ++s){
      const int K = 32*s + 8*t;
      const int k = (K >= 208) ? 2 : (K >= 104) ? 1 : 0;
      const int c0 = K - 104*k;
      const int aoff = (rbase + k)*104 + c0;
      const bf16x8 bvh = *(const bf16x8*)(bh + s*3584);
      const bf16x8 bvl = *(const bf16x8*)(bl + s*3584);
      const bf16x8 ah0 = *(const bf16x8*)(P3H + aoff);
      const bf16x8 al0 = *(const bf16x8*)(P3L + aoff);
      acc0 = MFMA16(ah0, bvh, acc0);
      acc0 = MFMA16(ah0, bvl, acc0);
      acc0 = MFMA16(al0, bvh, acc0);
      const bf16x8 ah1 = *(const bf16x8*)(P3H + aoff + 16*104);
      const bf16x8 al1 = *(const bf16x8*)(P3L + aoff + 16*104);
      acc1 = MFMA16(ah1, bvh, acc1);
      acc1 = MFMA16(ah1, bvl, acc1);
      acc1 = MFMA16(al1, bvh, acc1);
    }
    if (t == 0) acc0[0] = NEG;                // pool pad m=-1
    const float b4 = wf[W_CB4 + (o < 100 ? o : 0)];
    const float pu0 = (((t    ) % 3) == 1) ? fmaxf(acc0[0], acc0[1]) : acc0[0];
    const float pu1 = (((t + 4) % 3) == 1) ? fmaxf(acc1[0], acc1[1]) : acc1[0];
    #define ST4(jj, vv) { const int q_ = (jj); \
      if (q_ < 8 && o < 100){ float v_ = (vv) + b4; v_ = v_ > 0.f ? v_ : 0.01f*v_; \
        z[(size_t)g*900 + 100 + o*8 + q_] = v_; } }
    POOL_EMIT(0, acc0, pu0, pu1, ST4)
    POOL_EMIT(1, acc1, pu1, pu1, ST4)
    #undef ST4
  }
}

// ---------------- BatchNorm over batch axis (exact two-pass) ----------------
__global__ __launch_bounds__(256) void bn_kernel(float* __restrict__ z,
                                                 const float* __restrict__ wf){
  const int f = blockIdx.x;
  const int tid = threadIdx.x;
  float v[8];
  float s = 0.f;
  #pragma unroll
  for (int i = 0; i < 8; ++i){ v[i] = z[(size_t)(tid + i*256)*900 + f]; s += v[i]; }
  __shared__ float red[34];
  #pragma unroll
  for (int off = 32; off > 0; off >>= 1) s += __shfl_down(s, off);
  const int wave = tid >> 6, lane = tid & 63;
  if (lane == 0) red[wave] = s;
  __syncthreads();
  if (tid == 0) red[32] = (red[0]+red[1]+red[2]+red[3]) * (1.0f/2048.0f);
  __syncthreads();
  const float mu = red[32];
  float q = 0.f;
  #pragma unroll
  for (int i = 0; i < 8; ++i){ float d = v[i] - mu; q += d*d; }
  #pragma unroll
  for (int off = 32; off > 0; off >>= 1) q += __shfl_down(q, off);
  if (lane == 0) red[wave] = q;
  __syncthreads();
  if (tid == 0) red[33] = (red[0]+red[1]+red[2]+red[3]) * (1.0f/2048.0f);
  __syncthreads();
  const float var = red[33];
  const float scale = wf[W_BNG + f] / sqrtf(var + 1e-5f);
  const float shift = wf[W_BNB + f] - mu*scale;
  #pragma unroll
  for (int i = 0; i < 8; ++i) z[(size_t)(tid + i*256)*900 + f] = v[i]*scale + shift;
}

// ---------------- fc1 (900->256) + relu, 8 graphs/block (weight reuse) ------
__global__ __launch_bounds__(256) void fc1(const float* __restrict__ z,
                                           const float* __restrict__ wf,
                                           float* __restrict__ h1){
  const int n0 = blockIdx.x*8, tid = threadIdx.x;
  __shared__ __align__(16) float zr[8][900];
  for (int i = tid; i < 8*225; i += 256){
    int r = i / 225, c = i - r*225;
    ((float4*)&zr[r][0])[c] = ((const float4*)(z + (size_t)(n0 + r)*900))[c];
  }
  __syncthreads();
  const float* W = wf + W_FC1W + (size_t)tid*900;
  float acc[8];
  const float b = wf[W_FC1B + tid];
  #pragma unroll
  for (int r = 0; r < 8; ++r) acc[r] = b;
  #pragma unroll 2
  for (int k = 0; k < 900; k += 4){
    float4 wv = *(const float4*)(W + k);
    #pragma unroll
    for (int r = 0; r < 8; ++r)
      acc[r] += wv.x*zr[r][k] + wv.y*zr[r][k+1] + wv.z*zr[r][k+2] + wv.w*zr[r][k+3];
  }
  #pragma unroll
  for (int r = 0; r < 8; ++r)
    h1[(size_t)(n0 + r)*256 + tid] = fmaxf(acc[r], 0.f);
}

// ---------------- fc2 (256->64) + relu + fc3 (64->2), 4 graphs/block --------
__global__ __launch_bounds__(256) void fc23(const float* __restrict__ h1,
                                            const float* __restrict__ wf,
                                            const int* __restrict__ flag,
                                            void* __restrict__ outp){
  const int n0 = blockIdx.x*4, tid = threadIdx.x;
  __shared__ __align__(16) float hr[1024];
  __shared__ float sh2[4][64];
  const float4* src = (const float4*)(h1 + (size_t)n0*256);
  for (int i = tid; i < 256; i += 256) ((float4*)hr)[i] = src[i];
  __syncthreads();
  const int r = tid >> 6, o = tid & 63;
  const float* W = wf + W_FC2W + (size_t)o*256;
  float acc = wf[W_FC2B + o];
  #pragma unroll 4
  for (int k = 0; k < 256; k += 4){
    float4 wv = *(const float4*)(W + k);
    acc += wv.x*hr[r*256+k] + wv.y*hr[r*256+k+1] + wv.z*hr[r*256+k+2] + wv.w*hr[r*256+k+3];
  }
  sh2[r][o] = fmaxf(acc, 0.f);
  __syncthreads();
  if (tid < 8){
    const int rr = tid >> 1, j = tid & 1;
    const float* W3 = wf + W_FC3W + j*64;
    float a = wf[W_FC3B + j];
    #pragma unroll 8
    for (int k = 0; k < 64; ++k) a += sh2[rr][k]*W3[k];
    const int n = n0 + rr;
    if (flag[0]) ((unsigned short*)outp)[n*2 + j] = f2bf(a);
    else         ((float*)outp)[n*2 + j] = a;
  }
}

extern "C" void kernel_launch(void* const* d_in, const int* in_sizes, int n_in,
                              void* d_out, int out_size, void* d_ws, size_t ws_size,
                              hipStream_t stream){
  float* ws = (float*)d_ws;
  int* flag = (int*)(ws + WS_FLAG);
  const int E = in_sizes[2] / 2;

  detect_dtype<<<1, 64, 0, stream>>>((const unsigned int*)d_in[15], flag);
  hipMemsetAsync(ws + WS_CUR, 0, 2048*sizeof(int), stream);

  WP wp;
  for (int k = 0; k < 19; ++k) wp.p[k] = d_in[4 + k];
  cvt_weights<<<(W_TOT + 255)/256, 256, 0, stream>>>(wp, flag, ws + WS_WF);
  prep_bw<<<462, 256, 0, stream>>>(ws + WS_WF, (unsigned short*)(ws + WS_H1));

  edge_scatter<<<(E + 255)/256, 256, 0, stream>>>((const int*)d_in[2], (int*)(ws + WS_CUR),
                                                  (unsigned int*)(ws + WS_EBUF), E);
  graph_all<<<N_GRAPHS, 256, 0, stream>>>((const unsigned int*)(ws + WS_EBUF),
                                          (const int*)(ws + WS_CUR), d_in[0], flag,
                                          ws + WS_WF, ws + WS_Z);
  conv12_half<<<dim3(2, N_GRAPHS), 512, 0, stream>>>(d_in[1], flag, ws + WS_WF,
                                                     ws + WS_P2,
                                                     (const unsigned short*)(ws + WS_H1));
  conv34<<<N_GRAPHS, 512, 0, stream>>>(ws + WS_P2, ws + WS_WF,
                                       (const unsigned short*)(ws + WS_H1), ws + WS_Z);
  bn_kernel<<<900, 256, 0, stream>>>(ws + WS_Z, ws + WS_WF);
  fc1<<<N_GRAPHS/8, 256, 0, stream>>>(ws + WS_Z, ws + WS_WF, ws + WS_H1);
  fc23<<<N_GRAPHS/4, 256, 0, stream>>>(ws + WS_H1, ws + WS_WF, flag, d_out);
}

// Round 4
// 685.736 us; speedup vs baseline: 2.3894x; 1.2381x over previous
//
#include <hip/hip_runtime.h>

#define N_GRAPHS 2048
#define NSUB 8              // per-graph sub-buckets (one per XCD under default dispatch)
#define SCAP 256            // capacity per sub-bucket (mean 128 + 11 sigma)

// ---- workspace layout (float offsets) ----
// NOTE: P2 aliases EBUF+cur tail (edge pipeline fully completes before conv12 runs;
// next-iteration memset of cur only clobbers dead p2g bytes)
#define WS_CUR  0           // 16384 int (2048 graphs x 8 subs)
#define WS_EBUF 16384       // 2048*8*256 u32 (packed src|loc<<17)
#define WS_P2   2048        // p2g: 2048*67*100 f32 transposed [g][p][o] (aliases EBUF)
#define WS_Z    13723648    // 2048*900
#define WS_H1   15566848    // 2048*256 (fc1 out; ALSO hosts bw weights until conv34 done)
#define WS_WF   16091136    // converted f32 weights (347834)
#define WS_FLAG 16438970    // int flag

// ---- converted-weight offsets within wf ----
// conv weights stored TRANSPOSED: W[c][k][o]  (o fastest)
#define W_SAGE_WL 0
#define W_SAGE_BL 1000
#define W_SAGE_WR 1100
#define W_CW1     2100      // [21][3][100]
#define W_CB1     8400
#define W_CW2     8500      // [100][3][100]
#define W_CB2     38500
#define W_CW3     38600
#define W_CB3     68600
#define W_CW4     68700
#define W_CB4     98700
#define W_BNG     98800
#define W_BNB     99700
#define W_FC1W    100600
#define W_FC1B    331000
#define W_FC2W    331256
#define W_FC2B    347640
#define W_FC3W    347704
#define W_FC3B    347832
#define W_TOT     347834

// ---- MFMA fragment-layout conv weights (u16 offsets within bw = ws+WS_H1) ----
// layout Bw[Kchunk][o:112][8] bf16; K = k*CS + c
// conv1: CS=24, K'=96; conv2/3/4: CS=104, K'=320
#define BW2H_OFF 0
#define BW2L_OFF 35840
#define BW1H_OFF 71680
#define BW1L_OFF 82432
#define BW3H_OFF 93184
#define BW3L_OFF 129024
#define BW4H_OFF 164864
#define BW4L_OFF 200704
#define BW_TOT   236544     // u16 elems (473 KB, fits in H1 region)

typedef __attribute__((ext_vector_type(8))) short bf16x8;  // 8 bf16 (4 VGPRs)
typedef __attribute__((ext_vector_type(4))) float f32x4;   // MFMA accumulator

#define MFMA16(a, b, c) __builtin_amdgcn_mfma_f32_16x16x32_bf16((a), (b), (c), 0, 0, 0)

__device__ __forceinline__ float bf2f(unsigned short u){
  union { unsigned int ui; float f; } v; v.ui = ((unsigned int)u) << 16; return v.f;
}
__device__ __forceinline__ unsigned short f2bf(float f){
  union { float f; unsigned int ui; } v; v.f = f;
  unsigned int u = v.ui;
  return (unsigned short)((u + 0x7fffu + ((u >> 16) & 1u)) >> 16);
}
__device__ __forceinline__ float max3f(float a, float b, float c){
  return fmaxf(a, fmaxf(b, c));
}

// ---------------- dtype detection ----------------
__global__ void detect_dtype(const unsigned int* __restrict__ bng, int* __restrict__ flag){
  if (threadIdx.x == 0 && blockIdx.x == 0)
    flag[0] = (bng[0] == 0x3F803F80u) ? 1 : 0;   // bf16 "1.0,1.0" pair vs f32 1.0
}

// ---------------- weight conversion (+ conv transpose) ----------------
struct WP { const void* p[19]; };

__global__ __launch_bounds__(256) void cvt_weights(WP wp, const int* __restrict__ flag,
                                                   float* __restrict__ dst){
  const int i = blockIdx.x*256 + threadIdx.x;
  if (i >= W_TOT) return;
  const int isbf = flag[0];
  int seg = 0, off = i;
  #define SEGC(s, o) if (i >= (o)) { seg = (s); off = i - (o); }
  SEGC(1, W_SAGE_BL) SEGC(2, W_SAGE_WR) SEGC(3, W_CW1) SEGC(4, W_CB1)
  SEGC(5, W_CW2) SEGC(6, W_CB2) SEGC(7, W_CW3) SEGC(8, W_CB3)
  SEGC(9, W_CW4) SEGC(10, W_CB4) SEGC(11, W_BNG) SEGC(12, W_BNB)
  SEGC(13, W_FC1W) SEGC(14, W_FC1B) SEGC(15, W_FC2W) SEGC(16, W_FC2B)
  SEGC(17, W_FC3W) SEGC(18, W_FC3B)
  #undef SEGC
  int src = off;
  if (seg == 3){                         // conv1: dst [c][k][o] <- src [o][c][k], c<21
    int c = off / 300, r = off - c*300, k = r / 100, o = r - k*100;
    src = o*63 + c*3 + k;
  } else if (seg == 5 || seg == 7 || seg == 9){  // conv2/3/4: c<100
    int c = off / 300, r = off - c*300, k = r / 100, o = r - k*100;
    src = o*300 + c*3 + k;
  }
  if (isbf) dst[i] = bf2f(((const unsigned short*)wp.p[seg])[src]);
  else      dst[i] = ((const float*)wp.p[seg])[src];
}

// ---------------- MFMA weight prep: hi/lo bf16 split in fragment layout ---------
// B operand of mfma_f32_16x16x32_bf16: lane holds col=lane&15, K-chunk=(lane>>4)*8.
// Memory layout Bw[ch = K>>3][o][jj] so each lane reads one contiguous 16B chunk.
__global__ __launch_bounds__(256) void prep_bw(const float* __restrict__ wf,
                                               unsigned short* __restrict__ bw){
  const int i = blockIdx.x*256 + threadIdx.x;
  if (i >= 118272) return;   // 35840(c2) + 10752(c1) + 35840(c3) + 35840(c4)
  float w = 0.f; int hidx, lidx;
  if (i < 35840 || i >= 46592){          // conv2/3/4: K = k*104 + c, K' = 320
    int ii, wbase, hoff, loff;
    if (i < 35840)      { ii = i;         wbase = W_CW2; hoff = BW2H_OFF; loff = BW2L_OFF; }
    else if (i < 82432) { ii = i - 46592; wbase = W_CW3; hoff = BW3H_OFF; loff = BW3L_OFF; }
    else                { ii = i - 82432; wbase = W_CW4; hoff = BW4H_OFF; loff = BW4L_OFF; }
    const int jj = ii & 7, rest = ii >> 3;
    const int o = rest % 112, ch = rest / 112;
    const int K = ch*8 + jj;
    const int k = K / 104, c = K - k*104;
    if (K < 312 && c < 100 && o < 100) w = wf[wbase + c*300 + k*100 + o];
    hidx = hoff + ii; lidx = loff + ii;
  } else {                               // conv1: K = k*24 + c, K' = 96
    const int ii = i - 35840;
    const int jj = ii & 7, rest = ii >> 3;
    const int o = rest % 112, ch = rest / 112;
    const int K = ch*8 + jj;
    const int k = K / 24, c = K - k*24;
    if (K < 72 && c < 21 && o < 100) w = wf[W_CW1 + c*300 + k*100 + o];
    hidx = BW1H_OFF + ii; lidx = BW1L_OFF + ii;
  }
  const unsigned short hi = f2bf(w);
  bw[hidx] = hi;
  bw[lidx] = f2bf(w - bf2f(hi));         // residual: effective weight precision ~2^-18
}

// ---------------- edge bucketing: XCD-local sub-buckets ---------------------
// sub = blockIdx.x & 7 tracks the physical XCD under default round-robin
// dispatch, so every 64B line of a sub-bucket is written by ONE XCD's L2
// (2 MB footprint/XCD, L2-resident, full-line writeback). Fixes the 12.6x
// write amplification of the single-cursor scatter.
__global__ __launch_bounds__(256) void edge_scatter(const int* __restrict__ ei,
                                                    int* __restrict__ cur,
                                                    unsigned int* __restrict__ ebuf,
                                                    const int E){
  const int e = blockIdx.x*256 + threadIdx.x;
  if (e >= E) return;
  const unsigned int src = (unsigned int)ei[e];
  const int dst = ei[E + e];
  const int g = dst >> 6, loc = dst & 63;
  const int b = g*NSUB + (blockIdx.x & (NSUB-1));
  const int pos = atomicAdd(&cur[b], 1);
  if (pos < SCAP) ebuf[(size_t)b*SCAP + pos] = src | ((unsigned int)loc << 17);
}

// ---------------- per-graph SAGE (deg in LDS, weighted sum in regs) ----------
__global__ __launch_bounds__(256) void graph_all(const unsigned int* __restrict__ ebuf,
                                                 const int* __restrict__ cur,
                                                 const void* __restrict__ x1v,
                                                 const int* __restrict__ flag,
                                                 const float* __restrict__ wf,
                                                 float* __restrict__ z){
  const int g = blockIdx.x, tid = threadIdx.x;
  const int wave = tid >> 6, lane = tid & 63;
  __shared__ float degs[64];
  __shared__ float smp[40];
  __shared__ float sm[10], sx[10];
  __shared__ int scnt[9];
  if (tid < 64) degs[tid] = 0.f;
  if (tid == 0){
    int a = 0;
    #pragma unroll
    for (int s = 0; s < NSUB; ++s){ scnt[s] = a; a += min(cur[g*NSUB + s], SCAP); }
    scnt[NSUB] = a;
  }
  __syncthreads();
  const unsigned int* eb = ebuf + (size_t)g*(NSUB*SCAP);
  const int n = scnt[NSUB];
  const int isbf = flag[0];
  // flat index -> (sub, pos) via the 8-entry scan
  #define EB_AT(i_) eb[ ({ int s_ = 0; _Pragma("unroll") \
      for (int k_ = 1; k_ < NSUB; ++k_) s_ += ((i_) >= scnt[k_]); \
      s_*SCAP + (i_) - scnt[s_]; }) ]
  // pass1: per-node degree
  for (int e = tid; e < n; e += 256)
    atomicAdd(&degs[EB_AT(e) >> 17], 1.0f);
  __syncthreads();
  // pass2: gsum[f] = sum_e x1[src_e][f] / max(deg[dst_e],1)
  float acc[10];
  #pragma unroll
  for (int f = 0; f < 10; ++f) acc[f] = 0.f;
  for (int e = tid; e < n; e += 256){
    const unsigned int p = EB_AT(e);
    const unsigned int src = p & 0x1FFFFu;
    const float w = 1.0f / fmaxf(degs[p >> 17], 1.0f);
    if (isbf){
      const unsigned int* xr = (const unsigned int*)x1v + (size_t)src*5;
      #pragma unroll
      for (int k = 0; k < 5; ++k){
        unsigned int u = xr[k];
        acc[2*k]   += w * bf2f((unsigned short)(u & 0xffffu));
        acc[2*k+1] += w * bf2f((unsigned short)(u >> 16));
      }
    } else {
      const float2* xr = (const float2*)((const float*)x1v + (size_t)src*10);
      #pragma unroll
      for (int k = 0; k < 5; ++k){
        float2 u = xr[k];
        acc[2*k] += w*u.x; acc[2*k+1] += w*u.y;
      }
    }
  }
  #undef EB_AT
  #pragma unroll
  for (int f = 0; f < 10; ++f){
    float v = acc[f];
    #pragma unroll
    for (int o = 32; o > 0; o >>= 1) v += __shfl_down(v, o);
    if (lane == 0) smp[wave*10 + f] = v;
  }
  if (wave == 0){
    const int node = g*64 + lane;
    float xv[10];
    if (isbf){
      const unsigned int* xr = (const unsigned int*)x1v + (size_t)node*5;
      #pragma unroll
      for (int k = 0; k < 5; ++k){
        unsigned int u = xr[k];
        xv[2*k]   = bf2f((unsigned short)(u & 0xffffu));
        xv[2*k+1] = bf2f((unsigned short)(u >> 16));
      }
    } else {
      const float* xr = (const float*)x1v + (size_t)node*10;
      #pragma unroll
      for (int k = 0; k < 10; ++k) xv[k] = xr[k];
    }
    #pragma unroll
    for (int f = 0; f < 10; ++f){
      float v = xv[f];
      #pragma unroll
      for (int o = 32; o > 0; o >>= 1) v += __shfl_down(v, o);
      if (lane == 0) sx[f] = v;
    }
  }
  __syncthreads();
  if (tid < 10) sm[tid] = smp[tid] + smp[10+tid] + smp[20+tid] + smp[30+tid];
  __syncthreads();
  if (tid < 100){
    const float* Wl = wf + W_SAGE_WL + tid*10;
    const float* Wr = wf + W_SAGE_WR + tid*10;
    float a = 64.0f * wf[W_SAGE_BL + tid];
    #pragma unroll
    for (int k = 0; k < 10; ++k) a += sm[k]*Wl[k] + sx[k]*Wr[k];
    z[(size_t)g*900 + tid] = a;
  }
}

// ============================================================================
// MFMA conv machinery (verified R0/R1 on conv1/conv2). Swapped GEMM:
// A = im2col(input), rows = positions; B = W^T, cols = out-channels. D rows
// (4/lane-group) are consecutive positions -> pool3 done in registers.
// Supers = 48 rows = 16 pool windows. Lane-group G = 4*mt + t holds local rows
// 4G..4G+3; role = G%3 decides which windows this group owns.
// ============================================================================
#define POOL_EMIT(MT_, A_, PUA_, PUN_, ST_) { \
  const int G_ = (MT_)*4 + t; \
  const int a3_ = G_ / 3, role_ = G_ - a3_*3; \
  const float rdn_ = __shfl_down((PUA_), 16); \
  const float rnx_ = __shfl((PUN_), col); \
  const float rc_ = (t == 3) ? rnx_ : rdn_; \
  const float w1_ = max3f((A_)[0], (A_)[1], (A_)[2]); \
  const float w2_ = fmaxf((A_)[3], rc_); \
  const float w3_ = max3f((A_)[2], (A_)[3], rc_); \
  const float w4_ = max3f((A_)[1], (A_)[2], (A_)[3]); \
  const int j1_ = 4*a3_ + (role_ == 0 ? 0 : (role_ == 1 ? 2 : 3)); \
  const float v1_ = (role_ == 0 ? w1_ : (role_ == 1 ? w3_ : w4_)); \
  ST_(j1_, v1_) \
  if (role_ == 0) ST_((j1_ + 1), w2_) \
}

__global__ __launch_bounds__(512, 8) void conv12_half(const void* __restrict__ x2v,
                                                      const int* __restrict__ flag,
                                                      const float* __restrict__ wf,
                                                      float* __restrict__ p2g,
                                                      const unsigned short* __restrict__ bw){
  __shared__ __align__(16) unsigned char lds[40192];
  unsigned short* XT  = (unsigned short*)lds;             // [326][24]  x2 transposed, bf16
  unsigned short* P1T = (unsigned short*)(lds + 15648);   // [118][104] pool1 out transposed
  const int h = blockIdx.x, g = blockIdx.y, tid = threadIdx.x;
  const int wave = __builtin_amdgcn_readfirstlane(tid >> 6);
  const int lane = tid & 63;
  const int t = lane >> 4, col = lane & 15;
  const float NEG = -__builtin_inff();
  const int qs = h ? 100 : 0;
  const int nq = h ? 100 : 102;     // conv1/pool1 q-range computed by this half
  const int xs = h ? 300 : 0;

  // zero P1T (covers halo rows, c-padding 100..103, and all garbage-read rows)
  for (int i = tid; i < 6136; i += 512) ((unsigned int*)P1T)[i] = 0u;
  // stage X transposed: XT[xi][c] = x2[g][c][xs-1+xi], zero outside [0,600) / c>=21
  if (flag[0]){
    const unsigned short* src = (const unsigned short*)x2v + (size_t)g*12600;
    for (int i = tid; i < 21*326; i += 512){
      const int c = i / 326, xi = i - c*326;
      const int x = xs - 1 + xi;
      XT[xi*24 + c] = (x >= 0 && x < 600) ? src[c*600 + x] : (unsigned short)0;
    }
  } else {
    const float* src = (const float*)x2v + (size_t)g*12600;
    for (int i = tid; i < 21*326; i += 512){
      const int c = i / 326, xi = i - c*326;
      const int x = xs - 1 + xi;
      XT[xi*24 + c] = (x >= 0 && x < 600) ? f2bf(src[c*600 + x]) : (unsigned short)0;
    }
  }
  for (int i = tid; i < 326; i += 512){
    XT[i*24 + 21] = 0; XT[i*24 + 22] = 0; XT[i*24 + 23] = 0;
  }
  __syncthreads();

  // ---- conv1 (M=pos, N=100ch, K'=96) + pool1(pad0) -> P1T[q+2][c] ----
  for (int u = wave; u < 49; u += 8){
    const int sg = u / 7, nt = u - sg*7;
    const int o = nt*16 + col;
    const int MTn = (sg < 6) ? 3 : (h ? 1 : 2);
    f32x4 acc0 = {0.f,0.f,0.f,0.f}, acc1 = {0.f,0.f,0.f,0.f}, acc2 = {0.f,0.f,0.f,0.f};
    const unsigned short* bh = bw + BW1H_OFF + (size_t)(t*112 + o)*8;
    const unsigned short* bl = bw + BW1L_OFF + (size_t)(t*112 + o)*8;
    const int xbase = sg*48 + col;
    #pragma unroll
    for (int s = 0; s < 3; ++s){
      const int K = 32*s + 8*t;
      const int k = (K >= 72) ? 3 : (K >= 48) ? 2 : (K >= 24) ? 1 : 0;
      const int c0 = K - 24*k;
      const unsigned short* ap = XT + (xbase + k)*24 + c0;
      const bf16x8 av0 = *(const bf16x8*)ap;
      const bf16x8 bvh = *(const bf16x8*)(bh + s*3584);
      const bf16x8 bvl = *(const bf16x8*)(bl + s*3584);
      acc0 = MFMA16(av0, bvh, acc0);
      acc0 = MFMA16(av0, bvl, acc0);
      if (MTn > 1){
        const bf16x8 av1 = *(const bf16x8*)(ap + 16*24);
        acc1 = MFMA16(av1, bvh, acc1);
        acc1 = MFMA16(av1, bvl, acc1);
        if (MTn > 2){
          const bf16x8 av2 = *(const bf16x8*)(ap + 32*24);
          acc2 = MFMA16(av2, bvh, acc2);
          acc2 = MFMA16(av2, bvl, acc2);
        }
      }
    }
    const float b1 = wf[W_CB1 + (o < 100 ? o : 0)];
    const float pu0 = (((t    ) % 3) == 1) ? fmaxf(acc0[0], acc0[1]) : acc0[0];
    const float pu1 = (((t + 4) % 3) == 1) ? fmaxf(acc1[0], acc1[1]) : acc1[0];
    const float pu2 = (((t + 8) % 3) == 1) ? fmaxf(acc2[0], acc2[1]) : acc2[0];
    #define ST1(jj, vv) { const int q_ = sg*16 + (jj); \
      if (q_ < nq && o < 100){ float v_ = (vv) + b1; v_ = v_ > 0.f ? v_ : 0.01f*v_; \
        P1T[(2 + q_)*104 + o] = f2bf(v_); } }
    POOL_EMIT(0, acc0, pu0, pu1, ST1)
    if (MTn > 1) POOL_EMIT(1, acc1, pu1, pu2, ST1)
    if (MTn > 2) POOL_EMIT(2, acc2, pu2, pu2, ST1)
    #undef ST1
  }
  __syncthreads();

  // ---- conv2 (M=pos m, N=100ch, K'=320) + pool2(pad1) -> p2g[g][p][o] f32 ----
  const int pb = h ? 34 : 0;
  const int plim = h ? 67 : 34;
  for (int u = wave; u < 21; u += 8){
    const int sg = u / 7, nt = u - sg*7;
    const int o = nt*16 + col;
    const int m_b = (h ? 101 : -1) + sg*48;
    const int MTn = (sg < 2) ? 3 : 1;
    f32x4 acc0 = {0.f,0.f,0.f,0.f}, acc1 = {0.f,0.f,0.f,0.f}, acc2 = {0.f,0.f,0.f,0.f};
    const unsigned short* bh = bw + BW2H_OFF + (size_t)(t*112 + o)*8;
    const unsigned short* bl = bw + BW2L_OFF + (size_t)(t*112 + o)*8;
    const int rbase = m_b + col - qs + 1;     // P1T row for (mt=0, k=0)
    #pragma unroll
    for (int s = 0; s < 10; ++s){
      const int K = 32*s + 8*t;
      const int k = (K >= 208) ? 2 : (K >= 104) ? 1 : 0;
      const int c0 = K - 104*k;
      const unsigned short* ap = P1T + (rbase + k)*104 + c0;
      const bf16x8 av0 = *(const bf16x8*)ap;
      const bf16x8 bvh = *(const bf16x8*)(bh + s*3584);
      const bf16x8 bvl = *(const bf16x8*)(bl + s*3584);
      acc0 = MFMA16(av0, bvh, acc0);
      acc0 = MFMA16(av0, bvl, acc0);
      if (MTn > 1){
        const bf16x8 av1 = *(const bf16x8*)(ap + 16*104);
        acc1 = MFMA16(av1, bvh, acc1);
        acc1 = MFMA16(av1, bvl, acc1);
        const bf16x8 av2 = *(const bf16x8*)(ap + 32*104);
        acc2 = MFMA16(av2, bvh, acc2);
        acc2 = MFMA16(av2, bvl, acc2);
      }
    }
    if (h == 0 && sg == 0 && t == 0) acc0[0] = NEG;   // pool pad m=-1
    const float b2 = wf[W_CB2 + (o < 100 ? o : 0)];
    const float pu0 = (((t    ) % 3) == 1) ? fmaxf(acc0[0], acc0[1]) : acc0[0];
    const float pu1 = (((t + 4) % 3) == 1) ? fmaxf(acc1[0], acc1[1]) : acc1[0];
    const float pu2 = (((t + 8) % 3) == 1) ? fmaxf(acc2[0], acc2[1]) : acc2[0];
    #define ST2(jj, vv) { const int p_ = pb + sg*16 + (jj); \
      if (p_ < plim && o < 100){ float v_ = (vv) + b2; v_ = v_ > 0.f ? v_ : 0.01f*v_; \
        p2g[((size_t)g*67 + p_)*100 + o] = v_; } }
    POOL_EMIT(0, acc0, pu0, pu1, ST2)
    if (MTn > 1){
      POOL_EMIT(1, acc1, pu1, pu2, ST2)
      POOL_EMIT(2, acc2, pu2, pu2, ST2)
    }
    #undef ST2
  }
}

// ---------------- conv3+pool3+conv4+pool4 via MFMA, one block per graph -----
// Activations kept near-f32: LDS holds hi/lo bf16 pairs; each K-step does
// Ah*Bh + Ah*Bl + Al*Bh (dropped Al*Bl ~ 2^-16 relative).
__global__ __launch_bounds__(512, 4) void conv34(const float* __restrict__ p2g,
                                                 const float* __restrict__ wf,
                                                 const unsigned short* __restrict__ bw,
                                                 float* __restrict__ z){
  __shared__ __align__(16) unsigned char lds[48672];
  unsigned short* P2H = (unsigned short*)lds;            // [82][104], row = p+2
  unsigned short* P2L = (unsigned short*)(lds + 17056);
  unsigned short* P3H = (unsigned short*)(lds + 34112);  // [35][104], row = q+2
  unsigned short* P3L = (unsigned short*)(lds + 41392);
  const int g = blockIdx.x, tid = threadIdx.x;
  const int wave = __builtin_amdgcn_readfirstlane(tid >> 6);
  const int lane = tid & 63;
  const int t = lane >> 4, col = lane & 15;
  const float NEG = -__builtin_inff();

  // zero everything (halo rows, pad cols, garbage-read rows), then fill
  for (int i = tid; i < 12168; i += 512) ((unsigned int*)lds)[i] = 0u;
  __syncthreads();
  {
    const float* srcf = p2g + (size_t)g*6700;
    for (int i = tid; i < 6700; i += 512){
      const int p = i / 100, o = i - p*100;
      const float v = srcf[i];
      const unsigned short hi = f2bf(v);
      P2H[(p + 2)*104 + o] = hi;
      P2L[(p + 2)*104 + o] = f2bf(v - bf2f(hi));
    }
  }
  __syncthreads();

  // ---- conv3 (K'=320) + pool3(pad1): P2 -> P3[q+2][o], q in [0,23) ----
  for (int u = wave; u < 14; u += 8){
    const int sg = u / 7, nt = u - sg*7;
    const int o = nt*16 + col;
    const int m_b = -1 + 48*sg;
    const int MTn = sg ? 2 : 3;
    f32x4 acc0 = {0.f,0.f,0.f,0.f}, acc1 = {0.f,0.f,0.f,0.f}, acc2 = {0.f,0.f,0.f,0.f};
    const unsigned short* bh = bw + BW3H_OFF + (size_t)(t*112 + o)*8;
    const unsigned short* bl = bw + BW3L_OFF + (size_t)(t*112 + o)*8;
    const int rbase = m_b + col + 1;          // P2 row for (mt=0, k=0)
    #pragma unroll
    for (int s = 0; s < 10; ++s){
      const int K = 32*s + 8*t;
      const int k = (K >= 208) ? 2 : (K >= 104) ? 1 : 0;
      const int c0 = K - 104*k;
      const int aoff = (rbase + k)*104 + c0;
      const bf16x8 bvh = *(const bf16x8*)(bh + s*3584);
      const bf16x8 bvl = *(const bf16x8*)(bl + s*3584);
      const bf16x8 ah0 = *(const bf16x8*)(P2H + aoff);
      const bf16x8 al0 = *(const bf16x8*)(P2L + aoff);
      acc0 = MFMA16(ah0, bvh, acc0);
      acc0 = MFMA16(ah0, bvl, acc0);
      acc0 = MFMA16(al0, bvh, acc0);
      const bf16x8 ah1 = *(const bf16x8*)(P2H + aoff + 16*104);
      const bf16x8 al1 = *(const bf16x8*)(P2L + aoff + 16*104);
      acc1 = MFMA16(ah1, bvh, acc1);
      acc1 = MFMA16(ah1, bvl, acc1);
      acc1 = MFMA16(al1, bvh, acc1);
      if (MTn > 2){
        const bf16x8 ah2 = *(const bf16x8*)(P2H + aoff + 32*104);
        const bf16x8 al2 = *(const bf16x8*)(P2L + aoff + 32*104);
        acc2 = MFMA16(ah2, bvh, acc2);
        acc2 = MFMA16(ah2, bvl, acc2);
        acc2 = MFMA16(al2, bvh, acc2);
      }
    }
    if (sg == 0 && t == 0) acc0[0] = NEG;     // pool pad m=-1
    if (sg == 1 && t == 1) acc1[0] = NEG;     // pool pad m=67
    const float b3 = wf[W_CB3 + (o < 100 ? o : 0)];
    const float pu0 = (((t    ) % 3) == 1) ? fmaxf(acc0[0], acc0[1]) : acc0[0];
    const float pu1 = (((t + 4) % 3) == 1) ? fmaxf(acc1[0], acc1[1]) : acc1[0];
    const float pu2 = (((t + 8) % 3) == 1) ? fmaxf(acc2[0], acc2[1]) : acc2[0];
    #define ST3(jj, vv) { const int q_ = sg*16 + (jj); \
      if (q_ < 23 && o < 100){ float v_ = (vv) + b3; v_ = v_ > 0.f ? v_ : 0.01f*v_; \
        const unsigned short hi_ = f2bf(v_); \
        P3H[(2 + q_)*104 + o] = hi_; \
        P3L[(2 + q_)*104 + o] = f2bf(v_ - bf2f(hi_)); } }
    POOL_EMIT(0, acc0, pu0, pu1, ST3)
    POOL_EMIT(1, acc1, pu1, pu2, ST3)
    if (MTn > 2) POOL_EMIT(2, acc2, pu2, pu2, ST3)
    #undef ST3
  }
  __syncthreads();

  // ---- conv4 (K'=320) + pool4(pad1): P3 -> z[g][100 + o*8 + q], q in [0,8) ----
  if (wave < 7){
    const int o = wave*16 + col;
    f32x4 acc0 = {0.f,0.f,0.f,0.f}, acc1 = {0.f,0.f,0.f,0.f};
    const unsigned short* bh = bw + BW4H_OFF + (size_t)(t*112 + o)*8;
    const unsigned short* bl = bw + BW4L_OFF + (size_t)(t*112 + o)*8;
    const int rbase = col;                    // m_b = -1: row = m+1+k
    #pragma unroll
    for (int s = 0; s < 10; ++s){
      const int K = 32*s + 8*t;
      const int k = (K >= 208) ? 2 : (K >= 104) ? 1 : 0;
      const int c0 = K - 104*k;
      const int aoff = (rbase + k)*104 + c0;
      const bf16x8 bvh = *(const bf16x8*)(bh + s*3584);
      const bf16x8 bvl = *(const bf16x8*)(bl + s*3584);
      const bf16x8 ah0 = *(const bf16x8*)(P3H + aoff);
      const bf16x8 al0 = *(const bf16x8*)(P3L + aoff);
      acc0 = MFMA16(ah0, bvh, acc0);
      acc0 = MFMA16(ah0, bvl, acc0);
      acc0 = MFMA16(al0, bvh, acc0);
      const bf16x8 ah1 = *(const bf16x8*)(P3H + aoff + 16*104);
      const bf16x8 al1 = *(const bf16x8*)(P3L + aoff + 16*104);
      acc1 = MFMA16(ah1, bvh, acc1);
      acc1 = MFMA16(ah1, bvl, acc1);
      acc1 = MFMA16(al1, bvh, acc1);
    }
    if (t == 0) acc0[0] = NEG;                // pool pad m=-1
    const float b4 = wf[W_CB4 + (o < 100 ? o : 0)];
    const float pu0 = (((t    ) % 3) == 1) ? fmaxf(acc0[0], acc0[1]) : acc0[0];
    const float pu1 = (((t + 4) % 3) == 1) ? fmaxf(acc1[0], acc1[1]) : acc1[0];
    #define ST4(jj, vv) { const int q_ = (jj); \
      if (q_ < 8 && o < 100){ float v_ = (vv) + b4; v_ = v_ > 0.f ? v_ : 0.01f*v_; \
        z[(size_t)g*900 + 100 + o*8 + q_] = v_; } }
    POOL_EMIT(0, acc0, pu0, pu1, ST4)
    POOL_EMIT(1, acc1, pu1, pu1, ST4)
    #undef ST4
  }
}

// ---------------- BatchNorm over batch axis (exact two-pass) ----------------
__global__ __launch_bounds__(256) void bn_kernel(float* __restrict__ z,
                                                 const float* __restrict__ wf){
  const int f = blockIdx.x;
  const int tid = threadIdx.x;
  float v[8];
  float s = 0.f;
  #pragma unroll
  for (int i = 0; i < 8; ++i){ v[i] = z[(size_t)(tid + i*256)*900 + f]; s += v[i]; }
  __shared__ float red[34];
  #pragma unroll
  for (int off = 32; off > 0; off >>= 1) s += __shfl_down(s, off);
  const int wave = tid >> 6, lane = tid & 63;
  if (lane == 0) red[wave] = s;
  __syncthreads();
  if (tid == 0) red[32] = (red[0]+red[1]+red[2]+red[3]) * (1.0f/2048.0f);
  __syncthreads();
  const float mu = red[32];
  float q = 0.f;
  #pragma unroll
  for (int i = 0; i < 8; ++i){ float d = v[i] - mu; q += d*d; }
  #pragma unroll
  for (int off = 32; off > 0; off >>= 1) q += __shfl_down(q, off);
  if (lane == 0) red[wave] = q;
  __syncthreads();
  if (tid == 0) red[33] = (red[0]+red[1]+red[2]+red[3]) * (1.0f/2048.0f);
  __syncthreads();
  const float var = red[33];
  const float scale = wf[W_BNG + f] / sqrtf(var + 1e-5f);
  const float shift = wf[W_BNB + f] - mu*scale;
  #pragma unroll
  for (int i = 0; i < 8; ++i) z[(size_t)(tid + i*256)*900 + f] = v[i]*scale + shift;
}

// ---------------- fc1 (900->256) + relu, 8 graphs/block (weight reuse) ------
__global__ __launch_bounds__(256) void fc1(const float* __restrict__ z,
                                           const float* __restrict__ wf,
                                           float* __restrict__ h1){
  const int n0 = blockIdx.x*8, tid = threadIdx.x;
  __shared__ __align__(16) float zr[8][900];
  for (int i = tid; i < 8*225; i += 256){
    int r = i / 225, c = i - r*225;
    ((float4*)&zr[r][0])[c] = ((const float4*)(z + (size_t)(n0 + r)*900))[c];
  }
  __syncthreads();
  const float* W = wf + W_FC1W + (size_t)tid*900;
  float acc[8];
  const float b = wf[W_FC1B + tid];
  #pragma unroll
  for (int r = 0; r < 8; ++r) acc[r] = b;
  #pragma unroll 2
  for (int k = 0; k < 900; k += 4){
    float4 wv = *(const float4*)(W + k);
    #pragma unroll
    for (int r = 0; r < 8; ++r)
      acc[r] += wv.x*zr[r][k] + wv.y*zr[r][k+1] + wv.z*zr[r][k+2] + wv.w*zr[r][k+3];
  }
  #pragma unroll
  for (int r = 0; r < 8; ++r)
    h1[(size_t)(n0 + r)*256 + tid] = fmaxf(acc[r], 0.f);
}

// ---------------- fc2 (256->64) + relu + fc3 (64->2), 4 graphs/block --------
__global__ __launch_bounds__(256) void fc23(const float* __restrict__ h1,
                                            const float* __restrict__ wf,
                                            const int* __restrict__ flag,
                                            void* __restrict__ outp){
  const int n0 = blockIdx.x*4, tid = threadIdx.x;
  __shared__ __align__(16) float hr[1024];
  __shared__ float sh2[4][64];
  const float4* src = (const float4*)(h1 + (size_t)n0*256);
  for (int i = tid; i < 256; i += 256) ((float4*)hr)[i] = src[i];
  __syncthreads();
  const int r = tid >> 6, o = tid & 63;
  const float* W = wf + W_FC2W + (size_t)o*256;
  float acc = wf[W_FC2B + o];
  #pragma unroll 4
  for (int k = 0; k < 256; k += 4){
    float4 wv = *(const float4*)(W + k);
    acc += wv.x*hr[r*256+k] + wv.y*hr[r*256+k+1] + wv.z*hr[r*256+k+2] + wv.w*hr[r*256+k+3];
  }
  sh2[r][o] = fmaxf(acc, 0.f);
  __syncthreads();
  if (tid < 8){
    const int rr = tid >> 1, j = tid & 1;
    const float* W3 = wf + W_FC3W + j*64;
    float a = wf[W_FC3B + j];
    #pragma unroll 8
    for (int k = 0; k < 64; ++k) a += sh2[rr][k]*W3[k];
    const int n = n0 + rr;
    if (flag[0]) ((unsigned short*)outp)[n*2 + j] = f2bf(a);
    else         ((float*)outp)[n*2 + j] = a;
  }
}

extern "C" void kernel_launch(void* const* d_in, const int* in_sizes, int n_in,
                              void* d_out, int out_size, void* d_ws, size_t ws_size,
                              hipStream_t stream){
  float* ws = (float*)d_ws;
  int* flag = (int*)(ws + WS_FLAG);
  const int E = in_sizes[2] / 2;

  detect_dtype<<<1, 64, 0, stream>>>((const unsigned int*)d_in[15], flag);
  hipMemsetAsync(ws + WS_CUR, 0, N_GRAPHS*NSUB*sizeof(int), stream);

  WP wp;
  for (int k = 0; k < 19; ++k) wp.p[k] = d_in[4 + k];
  cvt_weights<<<(W_TOT + 255)/256, 256, 0, stream>>>(wp, flag, ws + WS_WF);
  prep_bw<<<462, 256, 0, stream>>>(ws + WS_WF, (unsigned short*)(ws + WS_H1));

  edge_scatter<<<(E + 255)/256, 256, 0, stream>>>((const int*)d_in[2], (int*)(ws + WS_CUR),
                                                  (unsigned int*)(ws + WS_EBUF), E);
  graph_all<<<N_GRAPHS, 256, 0, stream>>>((const unsigned int*)(ws + WS_EBUF),
                                          (const int*)(ws + WS_CUR), d_in[0], flag,
                                          ws + WS_WF, ws + WS_Z);
  conv12_half<<<dim3(2, N_GRAPHS), 512, 0, stream>>>(d_in[1], flag, ws + WS_WF,
                                                     ws + WS_P2,
                                                     (const unsigned short*)(ws + WS_H1));
  conv34<<<N_GRAPHS, 512, 0, stream>>>(ws + WS_P2, ws + WS_WF,
                                       (const unsigned short*)(ws + WS_H1), ws + WS_Z);
  bn_kernel<<<900, 256, 0, stream>>>(ws + WS_Z, ws + WS_WF);
  fc1<<<N_GRAPHS/8, 256, 0, stream>>>(ws + WS_Z, ws + WS_WF, ws + WS_H1);
  fc23<<<N_GRAPHS/4, 256, 0, stream>>>(ws + WS_H1, ws + WS_WF, flag, d_out);
}